// Round 1
// baseline (11690.609 us; speedup 1.0000x reference)
//
#include <hip/hip_runtime.h>
#include <cstdint>
#include <cstddef>

#define NN 50000      // nodes
#define NE 800000     // edges per path
#define NP 4          // metapaths
#define DD 256        // d_in = d_out
#define HH 128        // attention hidden

// ---------------- degree count (in-degree by dst) ----------------
__global__ __launch_bounds__(256) void k_deg(const int* __restrict__ edges,
                                             float* __restrict__ deg) {
    int i = blockIdx.x * 256 + threadIdx.x;
    if (i >= NP * NE) return;
    int p = i / NE;
    int e = i - p * NE;
    int dst = edges[(size_t)p * 2 * NE + NE + e];
    unsafeAtomicAdd(&deg[p * NN + dst], 1.0f);
}

// deg -> dinv = rsqrt(deg + 1)   (+1 = self loop), in place
__global__ __launch_bounds__(256) void k_dinv(float* __restrict__ deg) {
    int i = blockIdx.x * 256 + threadIdx.x;
    if (i >= NP * NN) return;
    deg[i] = rsqrtf(deg[i] + 1.0f);
}

// ---------------- fp32 tiled GEMM: C[NN][256] = A[NN][256] @ B[256][256] ----
__global__ __launch_bounds__(256) void k_gemm(const float* __restrict__ A,
                                              const float* __restrict__ B,
                                              float* __restrict__ C) {
    __shared__ __align__(16) float As[16][72];  // [k][m], stride 288B (16B-aligned)
    __shared__ __align__(16) float Bs[16][72];  // [k][n]
    const int tid = threadIdx.x;
    const int tx = tid & 15, ty = tid >> 4;
    const int bx = blockIdx.x;           // col tile 0..3
    const int by = blockIdx.y;           // row tile
    const int row0 = by * 64;
    const int arow = tid >> 2;           // 0..63
    const int akq  = tid & 3;            // 0..3
    const int brow = tid >> 4;           // 0..15
    const int bnq  = tid & 15;           // 0..15

    float acc[4][4] = {};
    for (int k0 = 0; k0 < 256; k0 += 16) {
        float4 va = make_float4(0.f, 0.f, 0.f, 0.f);
        int am = row0 + arow;
        if (am < NN) va = *(const float4*)(A + (size_t)am * 256 + k0 + akq * 4);
        float4 vb = *(const float4*)(B + (size_t)(k0 + brow) * 256 + bx * 64 + bnq * 4);
        __syncthreads();
        As[akq * 4 + 0][arow] = va.x;
        As[akq * 4 + 1][arow] = va.y;
        As[akq * 4 + 2][arow] = va.z;
        As[akq * 4 + 3][arow] = va.w;
        *(float4*)&Bs[brow][bnq * 4] = vb;
        __syncthreads();
#pragma unroll
        for (int kk = 0; kk < 16; kk++) {
            float4 a = *(const float4*)&As[kk][ty * 4];
            float4 b = *(const float4*)&Bs[kk][tx * 4];
            acc[0][0] += a.x * b.x; acc[0][1] += a.x * b.y; acc[0][2] += a.x * b.z; acc[0][3] += a.x * b.w;
            acc[1][0] += a.y * b.x; acc[1][1] += a.y * b.y; acc[1][2] += a.y * b.z; acc[1][3] += a.y * b.w;
            acc[2][0] += a.z * b.x; acc[2][1] += a.z * b.y; acc[2][2] += a.z * b.z; acc[2][3] += a.z * b.w;
            acc[3][0] += a.w * b.x; acc[3][1] += a.w * b.y; acc[3][2] += a.w * b.z; acc[3][3] += a.w * b.w;
        }
    }
#pragma unroll
    for (int i = 0; i < 4; i++) {
        int r = row0 + ty * 4 + i;
        if (r < NN) {
            float4 v = make_float4(acc[i][0], acc[i][1], acc[i][2], acc[i][3]);
            *(float4*)(C + (size_t)r * 256 + bx * 64 + tx * 4) = v;
        }
    }
}

// ---------------- edge scatter: z[dst] += norm * xw[src] --------------------
// one wave (64 lanes x float4 = 256 floats) per edge
__global__ __launch_bounds__(256) void k_scatter(const int* __restrict__ edges,  // path base [2][NE]
                                                 const float* __restrict__ dinv, // path base [NN]
                                                 const float* __restrict__ xw,
                                                 float* __restrict__ z) {        // path base [NN][256]
    int i = blockIdx.x * 256 + threadIdx.x;  // NE*64 threads
    int e = i >> 6;
    int lane = i & 63;
    if (e >= NE) return;
    int src = edges[e];
    int dst = edges[NE + e];
    float norm = dinv[src] * dinv[dst];
    float4 v = *(const float4*)(xw + (size_t)src * 256 + lane * 4);
    float* zp = z + (size_t)dst * 256 + lane * 4;
    unsafeAtomicAdd(zp + 0, v.x * norm);
    unsafeAtomicAdd(zp + 1, v.y * norm);
    unsafeAtomicAdd(zp + 2, v.z * norm);
    unsafeAtomicAdd(zp + 3, v.w * norm);
}

// ---------------- self-loop + bias epilogue ---------------------------------
__global__ __launch_bounds__(256) void k_selfloop(const float* __restrict__ dinv, // path base
                                                  const float* __restrict__ xw,
                                                  const float* __restrict__ bias, // bs path base [256]
                                                  float* __restrict__ z) {        // path base
    int i = blockIdx.x * 256 + threadIdx.x;  // NN*64 threads
    int n = i >> 6;
    int lane = i & 63;
    if (n >= NN) return;
    float dv = dinv[n];
    float d2 = dv * dv;
    float4 v  = *(const float4*)(xw + (size_t)n * 256 + lane * 4);
    float4 zz = *(const float4*)(z + (size_t)n * 256 + lane * 4);
    float4 bb = *(const float4*)(bias + lane * 4);
    zz.x += d2 * v.x + bb.x;
    zz.y += d2 * v.y + bb.y;
    zz.z += d2 * v.z + bb.z;
    zz.w += d2 * v.w + bb.w;
    *(float4*)(z + (size_t)n * 256 + lane * 4) = zz;
}

// ---------------- semantic attention + weighted sum -------------------------
// one block (128 threads) per node
__global__ __launch_bounds__(128) void k_attn(const float* __restrict__ z,  // [NP][NN][256]
                                              const float* __restrict__ w1, // [256][128]
                                              const float* __restrict__ b1, // [128]
                                              const float* __restrict__ w2, // [128]
                                              float* __restrict__ out) {    // [NN][256]
    int n = blockIdx.x;
    int j = threadIdx.x;  // 0..127
    __shared__ __align__(16) float zs[NP][DD];
    __shared__ float part[2][NP];

#pragma unroll
    for (int t = 0; t < 2; t++) {
        int fi = j + t * 128;          // 0..255 -> (path, quad)
        int p = fi >> 6, q = fi & 63;
        float4 v = *(const float4*)(z + ((size_t)p * NN + n) * 256 + q * 4);
        *(float4*)&zs[p][q * 4] = v;
    }
    __syncthreads();

    float a0 = 0.f, a1 = 0.f, a2 = 0.f, a3 = 0.f;
#pragma unroll 8
    for (int c = 0; c < 256; c++) {
        float w = w1[c * HH + j];
        a0 += zs[0][c] * w;
        a1 += zs[1][c] * w;
        a2 += zs[2][c] * w;
        a3 += zs[3][c] * w;
    }
    float bb = b1[j], wv = w2[j];
    float t0 = tanhf(a0 + bb) * wv;
    float t1 = tanhf(a1 + bb) * wv;
    float t2 = tanhf(a2 + bb) * wv;
    float t3 = tanhf(a3 + bb) * wv;
#pragma unroll
    for (int off = 32; off > 0; off >>= 1) {
        t0 += __shfl_down(t0, off);
        t1 += __shfl_down(t1, off);
        t2 += __shfl_down(t2, off);
        t3 += __shfl_down(t3, off);
    }
    int wid = j >> 6, lane = j & 63;
    if (lane == 0) {
        part[wid][0] = t0; part[wid][1] = t1; part[wid][2] = t2; part[wid][3] = t3;
    }
    __syncthreads();
    float s0 = part[0][0] + part[1][0];
    float s1 = part[0][1] + part[1][1];
    float s2 = part[0][2] + part[1][2];
    float s3 = part[0][3] + part[1][3];
    float m = fmaxf(fmaxf(s0, s1), fmaxf(s2, s3));
    float e0 = expf(s0 - m), e1 = expf(s1 - m), e2 = expf(s2 - m), e3 = expf(s3 - m);
    float r = 1.0f / (e0 + e1 + e2 + e3);
    float be0 = e0 * r, be1 = e1 * r, be2 = e2 * r, be3 = e3 * r;
#pragma unroll
    for (int t = 0; t < 2; t++) {
        int c = j + t * 128;
        out[(size_t)n * 256 + c] =
            be0 * zs[0][c] + be1 * zs[1][c] + be2 * zs[2][c] + be3 * zs[3][c];
    }
}

extern "C" void kernel_launch(void* const* d_in, const int* in_sizes, int n_in,
                              void* d_out, int out_size, void* d_ws, size_t ws_size,
                              hipStream_t stream) {
    const float* x     = (const float*)d_in[0];
    const int*   edges = (const int*)d_in[1];   // [4][2][800000]
    const float* Ws    = (const float*)d_in[2]; // [4][256][256]
    const float* bs    = (const float*)d_in[3]; // [4][256]
    const float* w1    = (const float*)d_in[4]; // [256][128]
    const float* b1    = (const float*)d_in[5]; // [128]
    const float* w2    = (const float*)d_in[6]; // [128]
    float* out = (float*)d_out;

    char* ws = (char*)d_ws;
    // layout: dinv (0.8MB) | xw (51.2MB, one path at a time) | z (204.8MB, all paths)
    float* dinv = (float*)ws;
    float* xw   = (float*)(ws + (1 << 20));
    float* z    = (float*)(ws + (1 << 20) + 52428800);

    hipMemsetAsync(dinv, 0, (size_t)NP * NN * sizeof(float), stream);
    hipMemsetAsync(z, 0, (size_t)NP * NN * DD * sizeof(float), stream);

    k_deg<<<(NP * NE + 255) / 256, 256, 0, stream>>>(edges, dinv);
    k_dinv<<<(NP * NN + 255) / 256, 256, 0, stream>>>(dinv);

    dim3 ggrid(4, (NN + 63) / 64, 1);
    for (int p = 0; p < NP; p++) {
        k_gemm<<<ggrid, 256, 0, stream>>>(x, Ws + (size_t)p * 256 * 256, xw);
        k_scatter<<<(NE * 64) / 256, 256, 0, stream>>>(
            edges + (size_t)p * 2 * NE, dinv + p * NN, xw, z + (size_t)p * NN * DD);
        k_selfloop<<<(NN * 64 + 255) / 256, 256, 0, stream>>>(
            dinv + p * NN, xw, bs + p * DD, z + (size_t)p * NN * DD);
    }
    k_attn<<<NN, 128, 0, stream>>>(z, w1, b1, w2, out);
}

// Round 2
// 3806.924 us; speedup vs baseline: 3.0709x; 3.0709x over previous
//
#include <hip/hip_runtime.h>
#include <cstdint>
#include <cstddef>

#define NN 50000      // nodes
#define NE 800000     // edges per path
#define NP 4          // metapaths
#define DD 256        // d_in = d_out
#define HH 128        // attention hidden

// ---------------- in-degree count (int, by dst) ----------------
__global__ __launch_bounds__(256) void k_deg(const int* __restrict__ edges,
                                             int* __restrict__ degi) {
    int i = blockIdx.x * 256 + threadIdx.x;
    if (i >= NP * NE) return;
    int p = i / NE;
    int e = i - p * NE;
    int dst = edges[(size_t)p * 2 * NE + NE + e];
    atomicAdd(&degi[p * NN + dst], 1);
}

// dinv = rsqrt(deg + 1)   (+1 = self loop)
__global__ __launch_bounds__(256) void k_dinv(const int* __restrict__ degi,
                                              float* __restrict__ dinv) {
    int i = blockIdx.x * 256 + threadIdx.x;
    if (i >= NP * NN) return;
    dinv[i] = rsqrtf((float)degi[i] + 1.0f);
}

// CSR range allocation: disjoint [off, off+deg) per node via per-path counter.
// Order is nondeterministic but coverage is exact (sum deg == NE per path).
__global__ __launch_bounds__(256) void k_alloc(const int* __restrict__ degi,
                                               int* __restrict__ cnt,
                                               int* __restrict__ offs,
                                               int* __restrict__ curs) {
    int i = blockIdx.x * 256 + threadIdx.x;
    if (i >= NP * NN) return;
    int p = i / NN;
    int d = degi[i];
    int off = atomicAdd(&cnt[p], d);
    offs[i] = off;
    curs[i] = off;
}

// fill srcs grouped by dst; after this, curs[i] == offs[i] + degi[i]
__global__ __launch_bounds__(256) void k_fill(const int* __restrict__ edges,
                                              int* __restrict__ curs,
                                              int* __restrict__ srcs) {
    int i = blockIdx.x * 256 + threadIdx.x;
    if (i >= NP * NE) return;
    int p = i / NE;
    int e = i - p * NE;
    int src = edges[(size_t)p * 2 * NE + e];
    int dst = edges[(size_t)p * 2 * NE + NE + e];
    int pos = atomicAdd(&curs[p * NN + dst], 1);
    srcs[(size_t)p * NE + pos] = src;
}

// ---------------- fp32 tiled GEMM with dinv-scale epilogue ------------------
// C[r] = dinv[r] * (A @ B)[r]
__global__ __launch_bounds__(256) void k_gemm(const float* __restrict__ A,
                                              const float* __restrict__ B,
                                              const float* __restrict__ dinv,
                                              float* __restrict__ C) {
    __shared__ __align__(16) float As[16][72];  // [k][m]
    __shared__ __align__(16) float Bs[16][72];  // [k][n]
    const int tid = threadIdx.x;
    const int tx = tid & 15, ty = tid >> 4;
    const int bx = blockIdx.x;           // col tile 0..3
    const int by = blockIdx.y;           // row tile
    const int row0 = by * 64;
    const int arow = tid >> 2;           // 0..63
    const int akq  = tid & 3;            // 0..3
    const int brow = tid >> 4;           // 0..15
    const int bnq  = tid & 15;           // 0..15

    float acc[4][4] = {};
    for (int k0 = 0; k0 < 256; k0 += 16) {
        float4 va = make_float4(0.f, 0.f, 0.f, 0.f);
        int am = row0 + arow;
        if (am < NN) va = *(const float4*)(A + (size_t)am * 256 + k0 + akq * 4);
        float4 vb = *(const float4*)(B + (size_t)(k0 + brow) * 256 + bx * 64 + bnq * 4);
        __syncthreads();
        As[akq * 4 + 0][arow] = va.x;
        As[akq * 4 + 1][arow] = va.y;
        As[akq * 4 + 2][arow] = va.z;
        As[akq * 4 + 3][arow] = va.w;
        *(float4*)&Bs[brow][bnq * 4] = vb;
        __syncthreads();
#pragma unroll
        for (int kk = 0; kk < 16; kk++) {
            float4 a = *(const float4*)&As[kk][ty * 4];
            float4 b = *(const float4*)&Bs[kk][tx * 4];
            acc[0][0] += a.x * b.x; acc[0][1] += a.x * b.y; acc[0][2] += a.x * b.z; acc[0][3] += a.x * b.w;
            acc[1][0] += a.y * b.x; acc[1][1] += a.y * b.y; acc[1][2] += a.y * b.z; acc[1][3] += a.y * b.w;
            acc[2][0] += a.z * b.x; acc[2][1] += a.z * b.y; acc[2][2] += a.z * b.z; acc[2][3] += a.z * b.w;
            acc[3][0] += a.w * b.x; acc[3][1] += a.w * b.y; acc[3][2] += a.w * b.z; acc[3][3] += a.w * b.w;
        }
    }
#pragma unroll
    for (int i = 0; i < 4; i++) {
        int r = row0 + ty * 4 + i;
        if (r < NN) {
            float dv = dinv[r];
            float4 v = make_float4(dv * acc[i][0], dv * acc[i][1],
                                   dv * acc[i][2], dv * acc[i][3]);
            *(float4*)(C + (size_t)r * 256 + bx * 64 + tx * 4) = v;
        }
    }
}

// ---------------- fused gather + self-loop + bias + semantic attention ------
// one wave per node; 4 waves (256 threads) per block
__global__ __launch_bounds__(256) void k_fused(const float* __restrict__ xws,  // [NP][NN][256] pre-scaled by dinv
                                               const float* __restrict__ dinv, // [NP][NN]
                                               const int* __restrict__ offs,   // [NP][NN]
                                               const int* __restrict__ ends,   // [NP][NN] (curs after fill)
                                               const int* __restrict__ srcs,   // [NP][NE]
                                               const float* __restrict__ bs,   // [NP][256]
                                               const float* __restrict__ w1,   // [256][128]
                                               const float* __restrict__ b1,   // [128]
                                               const float* __restrict__ w2,   // [128]
                                               float* __restrict__ out) {      // [NN][256]
    const int wid  = threadIdx.x >> 6;   // wave in block 0..3
    const int lane = threadIdx.x & 63;
    const int n = blockIdx.x * 4 + wid;  // NN = 12500*4 exactly

    __shared__ __align__(16) float zs[4][NP][DD];  // per-wave z tiles (wave-local)

    float4 zf[NP];

    // ---- gather phase: z_p = dinv_p[n] * (xws_p[n] + sum_in xws_p[src]) + b_p
#pragma unroll
    for (int p = 0; p < NP; p++) {
        const float* xp = xws + (size_t)p * NN * DD;
        const int* sp = srcs + (size_t)p * NE;
        float4 acc = *(const float4*)(xp + (size_t)n * DD + lane * 4);  // self loop
        int k  = offs[p * NN + n];
        int ke = ends[p * NN + n];
        for (; k + 4 <= ke; k += 4) {
            int s0 = sp[k], s1 = sp[k + 1], s2 = sp[k + 2], s3 = sp[k + 3];
            float4 v0 = *(const float4*)(xp + (size_t)s0 * DD + lane * 4);
            float4 v1 = *(const float4*)(xp + (size_t)s1 * DD + lane * 4);
            float4 v2 = *(const float4*)(xp + (size_t)s2 * DD + lane * 4);
            float4 v3 = *(const float4*)(xp + (size_t)s3 * DD + lane * 4);
            acc.x += v0.x + v1.x + v2.x + v3.x;
            acc.y += v0.y + v1.y + v2.y + v3.y;
            acc.z += v0.z + v1.z + v2.z + v3.z;
            acc.w += v0.w + v1.w + v2.w + v3.w;
        }
        for (; k < ke; k++) {
            int s = sp[k];
            float4 v = *(const float4*)(xp + (size_t)s * DD + lane * 4);
            acc.x += v.x; acc.y += v.y; acc.z += v.z; acc.w += v.w;
        }
        float dv = dinv[p * NN + n];
        float4 bb = *(const float4*)(bs + p * DD + lane * 4);
        float4 z;
        z.x = dv * acc.x + bb.x;
        z.y = dv * acc.y + bb.y;
        z.z = dv * acc.z + bb.z;
        z.w = dv * acc.w + bb.w;
        zf[p] = z;
        *(float4*)&zs[wid][p][lane * 4] = z;  // wave-local LDS, no barrier needed
    }

    // ---- attention phase: h_pj = sum_c z_p[c] * w1[c][j]; lane owns j=lane, j+64
    float a0[NP] = {}, a1[NP] = {};
#pragma unroll 4
    for (int c0 = 0; c0 < DD; c0 += 4) {
        float4 zv[NP];
#pragma unroll
        for (int p = 0; p < NP; p++) zv[p] = *(const float4*)&zs[wid][p][c0];
#pragma unroll
        for (int t = 0; t < 4; t++) {
            float wA = w1[(c0 + t) * HH + lane];
            float wB = w1[(c0 + t) * HH + lane + 64];
#pragma unroll
            for (int p = 0; p < NP; p++) {
                float zc = (t == 0) ? zv[p].x : (t == 1) ? zv[p].y : (t == 2) ? zv[p].z : zv[p].w;
                a0[p] += zc * wA;
                a1[p] += zc * wB;
            }
        }
    }
    float bA = b1[lane], bB = b1[lane + 64];
    float wvA = w2[lane], wvB = w2[lane + 64];
    float s[NP];
#pragma unroll
    for (int p = 0; p < NP; p++)
        s[p] = tanhf(a0[p] + bA) * wvA + tanhf(a1[p] + bB) * wvB;
    // butterfly reduce across the wave -> every lane holds the full sum
#pragma unroll
    for (int off = 1; off < 64; off <<= 1) {
#pragma unroll
        for (int p = 0; p < NP; p++) s[p] += __shfl_xor(s[p], off);
    }
    // softmax over the 4 paths (redundant on all lanes)
    float m = fmaxf(fmaxf(s[0], s[1]), fmaxf(s[2], s[3]));
    float e0 = __expf(s[0] - m), e1 = __expf(s[1] - m),
          e2 = __expf(s[2] - m), e3 = __expf(s[3] - m);
    float r = 1.0f / (e0 + e1 + e2 + e3);
    float be[NP] = {e0 * r, e1 * r, e2 * r, e3 * r};

    float4 o;
    o.x = be[0] * zf[0].x + be[1] * zf[1].x + be[2] * zf[2].x + be[3] * zf[3].x;
    o.y = be[0] * zf[0].y + be[1] * zf[1].y + be[2] * zf[2].y + be[3] * zf[3].y;
    o.z = be[0] * zf[0].z + be[1] * zf[1].z + be[2] * zf[2].z + be[3] * zf[3].z;
    o.w = be[0] * zf[0].w + be[1] * zf[1].w + be[2] * zf[2].w + be[3] * zf[3].w;
    *(float4*)(out + (size_t)n * DD + lane * 4) = o;
}

extern "C" void kernel_launch(void* const* d_in, const int* in_sizes, int n_in,
                              void* d_out, int out_size, void* d_ws, size_t ws_size,
                              hipStream_t stream) {
    const float* x     = (const float*)d_in[0];
    const int*   edges = (const int*)d_in[1];   // [4][2][800000]
    const float* Ws    = (const float*)d_in[2]; // [4][256][256]
    const float* bs    = (const float*)d_in[3]; // [4][256]
    const float* w1    = (const float*)d_in[4]; // [256][128]
    const float* b1    = (const float*)d_in[5]; // [128]
    const float* w2    = (const float*)d_in[6]; // [128]
    float* out = (float*)d_out;

    char* ws = (char*)d_ws;
    // layout (1 MiB-aligned regions):
    int*   degi = (int*)(ws);                       // 800 KB
    int*   cnt  = (int*)(ws + 800000);              // 16 B (zeroed with degi)
    float* dinv = (float*)(ws + (1 << 20));         // 800 KB
    int*   offs = (int*)(ws + (2 << 20));           // 800 KB
    int*   curs = (int*)(ws + (3 << 20));           // 800 KB
    int*   srcs = (int*)(ws + (4 << 20));           // 12.8 MB
    float* xws  = (float*)(ws + (18 << 20));        // 204.8 MB  -> total ~224 MB

    hipMemsetAsync(degi, 0, 800000 + 16, stream);

    k_deg  <<<(NP * NE + 255) / 256, 256, 0, stream>>>(edges, degi);
    k_dinv <<<(NP * NN + 255) / 256, 256, 0, stream>>>(degi, dinv);
    k_alloc<<<(NP * NN + 255) / 256, 256, 0, stream>>>(degi, cnt, offs, curs);
    k_fill <<<(NP * NE + 255) / 256, 256, 0, stream>>>(edges, curs, srcs);

    dim3 ggrid(4, (NN + 63) / 64, 1);
    for (int p = 0; p < NP; p++) {
        k_gemm<<<ggrid, 256, 0, stream>>>(x, Ws + (size_t)p * DD * DD,
                                          dinv + p * NN, xws + (size_t)p * NN * DD);
    }
    k_fused<<<NN / 4, 256, 0, stream>>>(xws, dinv, offs, curs, srcs,
                                        bs, w1, b1, w2, out);
}

// Round 3
// 1520.815 us; speedup vs baseline: 7.6871x; 2.5032x over previous
//
#include <hip/hip_runtime.h>
#include <cstdint>
#include <cstddef>

#define NN 50000      // nodes
#define NE 800000     // edges per path
#define NP 4          // metapaths
#define DD 256        // d_in = d_out
#define HH 128        // attention hidden

// ---------------- in-degree count (int, by dst) ----------------
__global__ __launch_bounds__(256) void k_deg(const int* __restrict__ edges,
                                             int* __restrict__ degi) {
    int i = blockIdx.x * 256 + threadIdx.x;
    if (i >= NP * NE) return;
    int p = i / NE;
    int e = i - p * NE;
    int dst = edges[(size_t)p * 2 * NE + NE + e];
    atomicAdd(&degi[p * NN + dst], 1);
}

// dinv = rsqrt(deg + 1)   (+1 = self loop)
__global__ __launch_bounds__(256) void k_dinv(const int* __restrict__ degi,
                                              float* __restrict__ dinv) {
    int i = blockIdx.x * 256 + threadIdx.x;
    if (i >= NP * NN) return;
    dinv[i] = rsqrtf((float)degi[i] + 1.0f);
}

// CSR range allocation via wave-aggregated atomics: 64-lane shfl scan of deg,
// ONE returning atomicAdd per wave on the per-path counter (cacheline-padded),
// lane offset = base + inclusive - d. Order nondeterministic, coverage exact.
__global__ __launch_bounds__(256) void k_alloc(const int* __restrict__ degi,
                                               int* __restrict__ cnt,   // stride 32 ints per path
                                               int* __restrict__ offs,
                                               int* __restrict__ curs) {
    const int p = blockIdx.y;
    const int i = blockIdx.x * 256 + threadIdx.x;   // node id within path
    const int lane = threadIdx.x & 63;
    const bool active = i < NN;
    int d = active ? degi[p * NN + i] : 0;
    int incl = d;
#pragma unroll
    for (int off = 1; off < 64; off <<= 1) {
        int v = __shfl_up(incl, off);
        if (lane >= off) incl += v;
    }
    int total = __shfl(incl, 63);
    int base = 0;
    if (lane == 0) base = atomicAdd(&cnt[p * 32], total);
    base = __shfl(base, 0);
    if (active) {
        int o = base + incl - d;
        offs[p * NN + i] = o;
        curs[p * NN + i] = o;
    }
}

// fill srcs grouped by dst; after this, curs[i] == offs[i] + degi[i]
__global__ __launch_bounds__(256) void k_fill(const int* __restrict__ edges,
                                              int* __restrict__ curs,
                                              int* __restrict__ srcs) {
    int i = blockIdx.x * 256 + threadIdx.x;
    if (i >= NP * NE) return;
    int p = i / NE;
    int e = i - p * NE;
    int src = edges[(size_t)p * 2 * NE + e];
    int dst = edges[(size_t)p * 2 * NE + NE + e];
    int pos = atomicAdd(&curs[p * NN + dst], 1);
    srcs[(size_t)p * NE + pos] = src;
}

// ---------------- fp32 tiled GEMM with dinv-scale epilogue ------------------
// C[r] = dinv[r] * (A @ B)[r]
__global__ __launch_bounds__(256) void k_gemm(const float* __restrict__ A,
                                              const float* __restrict__ B,
                                              const float* __restrict__ dinv,
                                              float* __restrict__ C) {
    __shared__ __align__(16) float As[16][72];  // [k][m]
    __shared__ __align__(16) float Bs[16][72];  // [k][n]
    const int tid = threadIdx.x;
    const int tx = tid & 15, ty = tid >> 4;
    const int bx = blockIdx.x;           // col tile 0..3
    const int by = blockIdx.y;           // row tile
    const int row0 = by * 64;
    const int arow = tid >> 2;           // 0..63
    const int akq  = tid & 3;            // 0..3
    const int brow = tid >> 4;           // 0..15
    const int bnq  = tid & 15;           // 0..15

    float acc[4][4] = {};
    for (int k0 = 0; k0 < 256; k0 += 16) {
        float4 va = make_float4(0.f, 0.f, 0.f, 0.f);
        int am = row0 + arow;
        if (am < NN) va = *(const float4*)(A + (size_t)am * 256 + k0 + akq * 4);
        float4 vb = *(const float4*)(B + (size_t)(k0 + brow) * 256 + bx * 64 + bnq * 4);
        __syncthreads();
        As[akq * 4 + 0][arow] = va.x;
        As[akq * 4 + 1][arow] = va.y;
        As[akq * 4 + 2][arow] = va.z;
        As[akq * 4 + 3][arow] = va.w;
        *(float4*)&Bs[brow][bnq * 4] = vb;
        __syncthreads();
#pragma unroll
        for (int kk = 0; kk < 16; kk++) {
            float4 a = *(const float4*)&As[kk][ty * 4];
            float4 b = *(const float4*)&Bs[kk][tx * 4];
            acc[0][0] += a.x * b.x; acc[0][1] += a.x * b.y; acc[0][2] += a.x * b.z; acc[0][3] += a.x * b.w;
            acc[1][0] += a.y * b.x; acc[1][1] += a.y * b.y; acc[1][2] += a.y * b.z; acc[1][3] += a.y * b.w;
            acc[2][0] += a.z * b.x; acc[2][1] += a.z * b.y; acc[2][2] += a.z * b.z; acc[2][3] += a.z * b.w;
            acc[3][0] += a.w * b.x; acc[3][1] += a.w * b.y; acc[3][2] += a.w * b.z; acc[3][3] += a.w * b.w;
        }
    }
#pragma unroll
    for (int i = 0; i < 4; i++) {
        int r = row0 + ty * 4 + i;
        if (r < NN) {
            float dv = dinv[r];
            float4 v = make_float4(dv * acc[i][0], dv * acc[i][1],
                                   dv * acc[i][2], dv * acc[i][3]);
            *(float4*)(C + (size_t)r * 256 + bx * 64 + tx * 4) = v;
        }
    }
}

// ---------------- fused gather + self-loop + bias + semantic attention ------
// one wave per node; 4 waves (256 threads) per block
__global__ __launch_bounds__(256) void k_fused(const float* __restrict__ xws,  // [NP][NN][256] pre-scaled by dinv
                                               const float* __restrict__ dinv, // [NP][NN]
                                               const int* __restrict__ offs,   // [NP][NN]
                                               const int* __restrict__ ends,   // [NP][NN] (curs after fill)
                                               const int* __restrict__ srcs,   // [NP][NE]
                                               const float* __restrict__ bs,   // [NP][256]
                                               const float* __restrict__ w1,   // [256][128]
                                               const float* __restrict__ b1,   // [128]
                                               const float* __restrict__ w2,   // [128]
                                               float* __restrict__ out) {      // [NN][256]
    const int wid  = threadIdx.x >> 6;   // wave in block 0..3
    const int lane = threadIdx.x & 63;
    const int n = blockIdx.x * 4 + wid;  // NN = 12500*4 exactly

    __shared__ __align__(16) float zs[4][NP][DD];  // per-wave z tiles (wave-local)

    float4 zf[NP];

    // ---- gather phase: z_p = dinv_p[n] * (xws_p[n] + sum_in xws_p[src]) + b_p
#pragma unroll
    for (int p = 0; p < NP; p++) {
        const float* xp = xws + (size_t)p * NN * DD;
        const int* sp = srcs + (size_t)p * NE;
        float4 acc = *(const float4*)(xp + (size_t)n * DD + lane * 4);  // self loop
        int k  = offs[p * NN + n];
        int ke = ends[p * NN + n];
        for (; k + 4 <= ke; k += 4) {
            int s0 = sp[k], s1 = sp[k + 1], s2 = sp[k + 2], s3 = sp[k + 3];
            float4 v0 = *(const float4*)(xp + (size_t)s0 * DD + lane * 4);
            float4 v1 = *(const float4*)(xp + (size_t)s1 * DD + lane * 4);
            float4 v2 = *(const float4*)(xp + (size_t)s2 * DD + lane * 4);
            float4 v3 = *(const float4*)(xp + (size_t)s3 * DD + lane * 4);
            acc.x += v0.x + v1.x + v2.x + v3.x;
            acc.y += v0.y + v1.y + v2.y + v3.y;
            acc.z += v0.z + v1.z + v2.z + v3.z;
            acc.w += v0.w + v1.w + v2.w + v3.w;
        }
        for (; k < ke; k++) {
            int s = sp[k];
            float4 v = *(const float4*)(xp + (size_t)s * DD + lane * 4);
            acc.x += v.x; acc.y += v.y; acc.z += v.z; acc.w += v.w;
        }
        float dv = dinv[p * NN + n];
        float4 bb = *(const float4*)(bs + p * DD + lane * 4);
        float4 z;
        z.x = dv * acc.x + bb.x;
        z.y = dv * acc.y + bb.y;
        z.z = dv * acc.z + bb.z;
        z.w = dv * acc.w + bb.w;
        zf[p] = z;
        *(float4*)&zs[wid][p][lane * 4] = z;  // wave-local LDS, no barrier needed
    }

    // ---- attention phase: h_pj = sum_c z_p[c] * w1[c][j]; lane owns j=lane, j+64
    float a0[NP] = {}, a1[NP] = {};
#pragma unroll 4
    for (int c0 = 0; c0 < DD; c0 += 4) {
        float4 zv[NP];
#pragma unroll
        for (int p = 0; p < NP; p++) zv[p] = *(const float4*)&zs[wid][p][c0];
#pragma unroll
        for (int t = 0; t < 4; t++) {
            float wA = w1[(c0 + t) * HH + lane];
            float wB = w1[(c0 + t) * HH + lane + 64];
#pragma unroll
            for (int p = 0; p < NP; p++) {
                float zc = (t == 0) ? zv[p].x : (t == 1) ? zv[p].y : (t == 2) ? zv[p].z : zv[p].w;
                a0[p] += zc * wA;
                a1[p] += zc * wB;
            }
        }
    }
    float bA = b1[lane], bB = b1[lane + 64];
    float wvA = w2[lane], wvB = w2[lane + 64];
    float s[NP];
#pragma unroll
    for (int p = 0; p < NP; p++)
        s[p] = tanhf(a0[p] + bA) * wvA + tanhf(a1[p] + bB) * wvB;
    // butterfly reduce across the wave -> every lane holds the full sum
#pragma unroll
    for (int off = 1; off < 64; off <<= 1) {
#pragma unroll
        for (int p = 0; p < NP; p++) s[p] += __shfl_xor(s[p], off);
    }
    // softmax over the 4 paths (redundant on all lanes)
    float m = fmaxf(fmaxf(s[0], s[1]), fmaxf(s[2], s[3]));
    float e0 = __expf(s[0] - m), e1 = __expf(s[1] - m),
          e2 = __expf(s[2] - m), e3 = __expf(s[3] - m);
    float r = 1.0f / (e0 + e1 + e2 + e3);
    float be[NP] = {e0 * r, e1 * r, e2 * r, e3 * r};

    float4 o;
    o.x = be[0] * zf[0].x + be[1] * zf[1].x + be[2] * zf[2].x + be[3] * zf[3].x;
    o.y = be[0] * zf[0].y + be[1] * zf[1].y + be[2] * zf[2].y + be[3] * zf[3].y;
    o.z = be[0] * zf[0].z + be[1] * zf[1].z + be[2] * zf[2].z + be[3] * zf[3].z;
    o.w = be[0] * zf[0].w + be[1] * zf[1].w + be[2] * zf[2].w + be[3] * zf[3].w;
    *(float4*)(out + (size_t)n * DD + lane * 4) = o;
}

extern "C" void kernel_launch(void* const* d_in, const int* in_sizes, int n_in,
                              void* d_out, int out_size, void* d_ws, size_t ws_size,
                              hipStream_t stream) {
    const float* x     = (const float*)d_in[0];
    const int*   edges = (const int*)d_in[1];   // [4][2][800000]
    const float* Ws    = (const float*)d_in[2]; // [4][256][256]
    const float* bs    = (const float*)d_in[3]; // [4][256]
    const float* w1    = (const float*)d_in[4]; // [256][128]
    const float* b1    = (const float*)d_in[5]; // [128]
    const float* w2    = (const float*)d_in[6]; // [128]
    float* out = (float*)d_out;

    char* ws = (char*)d_ws;
    // layout (1 MiB-aligned regions):
    int*   degi = (int*)(ws);                       // 800 KB
    int*   cnt  = (int*)(ws + 800000);              // 4 paths x 128B stride
    float* dinv = (float*)(ws + (1 << 20));         // 800 KB
    int*   offs = (int*)(ws + (2 << 20));           // 800 KB
    int*   curs = (int*)(ws + (3 << 20));           // 800 KB
    int*   srcs = (int*)(ws + (4 << 20));           // 12.8 MB
    float* xws  = (float*)(ws + (18 << 20));        // 204.8 MB  -> total ~224 MB

    hipMemsetAsync(degi, 0, 800000 + 512, stream);

    k_deg  <<<(NP * NE + 255) / 256, 256, 0, stream>>>(edges, degi);
    k_dinv <<<(NP * NN + 255) / 256, 256, 0, stream>>>(degi, dinv);
    dim3 agrid((NN + 255) / 256, NP);
    k_alloc<<<agrid, 256, 0, stream>>>(degi, cnt, offs, curs);
    k_fill <<<(NP * NE + 255) / 256, 256, 0, stream>>>(edges, curs, srcs);

    dim3 ggrid(4, (NN + 63) / 64, 1);
    for (int p = 0; p < NP; p++) {
        k_gemm<<<ggrid, 256, 0, stream>>>(x, Ws + (size_t)p * DD * DD,
                                          dinv + p * NN, xws + (size_t)p * NN * DD);
    }
    k_fused<<<NN / 4, 256, 0, stream>>>(xws, dinv, offs, curs, srcs,
                                        bs, w1, b1, w2, out);
}

// Round 4
// 1178.138 us; speedup vs baseline: 9.9230x; 1.2909x over previous
//
#include <hip/hip_runtime.h>
#include <hip/hip_fp16.h>
#include <cstdint>
#include <cstddef>

#define NN 50000      // nodes
#define NE 800000     // edges per path
#define NP 4          // metapaths
#define DD 256        // d_in = d_out
#define HH 128        // attention hidden
#define MPAD 50048    // NN rounded up to 64 (782*64)

typedef _Float16 f16x8 __attribute__((ext_vector_type(8)));
typedef float f32x4 __attribute__((ext_vector_type(4)));

// ---------------- x (fp32) -> xh (f16), 8 elems/thread ----------------------
__global__ __launch_bounds__(256) void k_cvt_x(const float* __restrict__ x,
                                               _Float16* __restrict__ xh) {
    int i = blockIdx.x * 256 + threadIdx.x;     // one octet of elements
    if (i >= NN * DD / 8) return;
    const float4* src = (const float4*)x + (size_t)i * 2;
    float4 v0 = src[0], v1 = src[1];
    f16x8 o;
    o[0] = (_Float16)v0.x; o[1] = (_Float16)v0.y; o[2] = (_Float16)v0.z; o[3] = (_Float16)v0.w;
    o[4] = (_Float16)v1.x; o[5] = (_Float16)v1.y; o[6] = (_Float16)v1.z; o[7] = (_Float16)v1.w;
    *((f16x8*)xh + i) = o;
}

// ---------------- Ws [p][k][n] fp32 -> Wt [p][n][k] f16 ---------------------
__global__ __launch_bounds__(256) void k_cvt_w(const float* __restrict__ Ws,
                                               _Float16* __restrict__ Wt) {
    int i = blockIdx.x * 256 + threadIdx.x;     // (p, n, k-octet)
    if (i >= NP * DD * DD / 8) return;
    int p   = i / (DD * DD / 8);
    int rem = i - p * (DD * DD / 8);
    int n   = rem >> 5;
    int k8  = (rem & 31) * 8;
    const float* wp = Ws + (size_t)p * DD * DD;
    f16x8 o;
#pragma unroll
    for (int t = 0; t < 8; t++) o[t] = (_Float16)wp[(size_t)(k8 + t) * DD + n];
    *((f16x8*)(Wt + (size_t)p * DD * DD + (size_t)n * DD + k8)) = o;
}

// ---------------- in-degree count (int, by dst) ----------------
__global__ __launch_bounds__(256) void k_deg(const int* __restrict__ edges,
                                             int* __restrict__ degi) {
    int i = blockIdx.x * 256 + threadIdx.x;
    if (i >= NP * NE) return;
    int p = i / NE;
    int e = i - p * NE;
    int dst = edges[(size_t)p * 2 * NE + NE + e];
    atomicAdd(&degi[p * NN + dst], 1);
}

// dinv = rsqrt(deg + 1)   (+1 = self loop)
__global__ __launch_bounds__(256) void k_dinv(const int* __restrict__ degi,
                                              float* __restrict__ dinv) {
    int i = blockIdx.x * 256 + threadIdx.x;
    if (i >= NP * NN) return;
    dinv[i] = rsqrtf((float)degi[i] + 1.0f);
}

// CSR range allocation via wave-aggregated atomics (one atomic per wave).
__global__ __launch_bounds__(256) void k_alloc(const int* __restrict__ degi,
                                               int* __restrict__ cnt,   // stride 32 ints per path
                                               int* __restrict__ offs,
                                               int* __restrict__ curs) {
    const int p = blockIdx.y;
    const int i = blockIdx.x * 256 + threadIdx.x;
    const int lane = threadIdx.x & 63;
    const bool active = i < NN;
    int d = active ? degi[p * NN + i] : 0;
    int incl = d;
#pragma unroll
    for (int off = 1; off < 64; off <<= 1) {
        int v = __shfl_up(incl, off);
        if (lane >= off) incl += v;
    }
    int total = __shfl(incl, 63);
    int base = 0;
    if (lane == 0) base = atomicAdd(&cnt[p * 32], total);
    base = __shfl(base, 0);
    if (active) {
        int o = base + incl - d;
        offs[p * NN + i] = o;
        curs[p * NN + i] = o;
    }
}

// fill srcs grouped by dst; after this, curs[i] == offs[i] + degi[i]
__global__ __launch_bounds__(256) void k_fill(const int* __restrict__ edges,
                                              int* __restrict__ curs,
                                              int* __restrict__ srcs) {
    int i = blockIdx.x * 256 + threadIdx.x;
    if (i >= NP * NE) return;
    int p = i / NE;
    int e = i - p * NE;
    int src = edges[(size_t)p * 2 * NE + e];
    int dst = edges[(size_t)p * 2 * NE + NE + e];
    int pos = atomicAdd(&curs[p * NN + dst], 1);
    srcs[(size_t)p * NE + pos] = src;
}

// ---------------- f16 MFMA GEMM: xws = f16(dinv * (xh @ W)) -----------------
// block = 4 waves; block tile 64 rows x 256 cols; wave w owns cols [w*64, w*64+64)
// A frag: A[m=lane&15][k=quad*8+j]; B frag: B[n=lane&15][k=quad*8+j] (Wt is [n][k])
// D frag: col=lane&15, row=quad*4+reg
__global__ __launch_bounds__(256) void k_gemm_mfma(const _Float16* __restrict__ xh,  // [MPAD][256]
                                                   const _Float16* __restrict__ Wt,  // [NP][256 n][256 k]
                                                   const float* __restrict__ dinv,   // [NP][NN]
                                                   _Float16* __restrict__ xws) {     // [NP][NN][256]
    const int p    = blockIdx.y;
    const int wv   = threadIdx.x >> 6;
    const int lane = threadIdx.x & 63;
    const int m_base = blockIdx.x * 64;
    const int n0   = wv * 64;
    const int mr   = lane & 15;
    const int quad = lane >> 4;

    const _Float16* ap = xh + (size_t)(m_base + mr) * DD + quad * 8;
    const _Float16* bp = Wt + (size_t)p * DD * DD + (size_t)(n0 + mr) * DD + quad * 8;
    const float* dv = dinv + (size_t)p * NN;
    _Float16* cp = xws + (size_t)p * NN * DD;

    f32x4 acc[4][4] = {};   // [m-tile][n-tile]
    for (int k0 = 0; k0 < DD; k0 += 32) {
        f16x8 a[4], b[4];
#pragma unroll
        for (int i = 0; i < 4; i++) a[i] = *(const f16x8*)(ap + (size_t)i * 16 * DD + k0);
#pragma unroll
        for (int j = 0; j < 4; j++) b[j] = *(const f16x8*)(bp + (size_t)j * 16 * DD + k0);
#pragma unroll
        for (int i = 0; i < 4; i++)
#pragma unroll
            for (int j = 0; j < 4; j++)
                acc[i][j] = __builtin_amdgcn_mfma_f32_16x16x32_f16(a[i], b[j], acc[i][j], 0, 0, 0);
    }
#pragma unroll
    for (int i = 0; i < 4; i++) {
#pragma unroll
        for (int r = 0; r < 4; r++) {
            int row = m_base + i * 16 + quad * 4 + r;
            if (row < NN) {
                float d = dv[row];
#pragma unroll
                for (int j = 0; j < 4; j++)
                    cp[(size_t)row * DD + n0 + j * 16 + mr] = (_Float16)(d * acc[i][j][r]);
            }
        }
    }
}

// ---------------- fused gather + self-loop + bias + semantic attention ------
// one wave per node; 4 waves (256 threads) per block; xws is f16
__global__ __launch_bounds__(256) void k_fused(const __half* __restrict__ xws,  // [NP][NN][256] f16, dinv-scaled
                                               const float* __restrict__ dinv,  // [NP][NN]
                                               const int* __restrict__ offs,    // [NP][NN]
                                               const int* __restrict__ ends,    // [NP][NN]
                                               const int* __restrict__ srcs,    // [NP][NE]
                                               const float* __restrict__ bs,    // [NP][256]
                                               const float* __restrict__ w1,    // [256][128]
                                               const float* __restrict__ b1,    // [128]
                                               const float* __restrict__ w2,    // [128]
                                               float* __restrict__ out) {       // [NN][256]
    const int wid  = threadIdx.x >> 6;
    const int lane = threadIdx.x & 63;
    const int n = blockIdx.x * 4 + wid;

    __shared__ __align__(16) float zs[4][NP][DD];

    union H4 { uint2 u; __half2 h[2]; };

    float4 zf[NP];

#pragma unroll
    for (int p = 0; p < NP; p++) {
        const uint2* xp = (const uint2*)(xws + (size_t)p * NN * DD);  // 4 halves per uint2
        const int* sp = srcs + (size_t)p * NE;
        H4 acc; acc.u = xp[(size_t)n * 64 + lane];   // self loop
        int k  = offs[p * NN + n];
        int ke = ends[p * NN + n];
        for (; k + 4 <= ke; k += 4) {
            int s0 = sp[k], s1 = sp[k + 1], s2 = sp[k + 2], s3 = sp[k + 3];
            H4 v0, v1, v2, v3;
            v0.u = xp[(size_t)s0 * 64 + lane];
            v1.u = xp[(size_t)s1 * 64 + lane];
            v2.u = xp[(size_t)s2 * 64 + lane];
            v3.u = xp[(size_t)s3 * 64 + lane];
            acc.h[0] = __hadd2(acc.h[0], __hadd2(__hadd2(v0.h[0], v1.h[0]), __hadd2(v2.h[0], v3.h[0])));
            acc.h[1] = __hadd2(acc.h[1], __hadd2(__hadd2(v0.h[1], v1.h[1]), __hadd2(v2.h[1], v3.h[1])));
        }
        for (; k < ke; k++) {
            H4 v; v.u = xp[(size_t)sp[k] * 64 + lane];
            acc.h[0] = __hadd2(acc.h[0], v.h[0]);
            acc.h[1] = __hadd2(acc.h[1], v.h[1]);
        }
        float dv = dinv[p * NN + n];
        float4 bb = *(const float4*)(bs + p * DD + lane * 4);
        float2 f0 = __half22float2(acc.h[0]);
        float2 f1 = __half22float2(acc.h[1]);
        float4 z;
        z.x = dv * f0.x + bb.x;
        z.y = dv * f0.y + bb.y;
        z.z = dv * f1.x + bb.z;
        z.w = dv * f1.y + bb.w;
        zf[p] = z;
        *(float4*)&zs[wid][p][lane * 4] = z;  // wave-local, no barrier needed
    }

    // ---- attention: h_pj = sum_c z_p[c] * w1[c][j]; lane owns j=lane, j+64
    float a0[NP] = {}, a1[NP] = {};
#pragma unroll 4
    for (int c0 = 0; c0 < DD; c0 += 4) {
        float4 zv[NP];
#pragma unroll
        for (int p = 0; p < NP; p++) zv[p] = *(const float4*)&zs[wid][p][c0];
#pragma unroll
        for (int t = 0; t < 4; t++) {
            float wA = w1[(c0 + t) * HH + lane];
            float wB = w1[(c0 + t) * HH + lane + 64];
#pragma unroll
            for (int p = 0; p < NP; p++) {
                float zc = (t == 0) ? zv[p].x : (t == 1) ? zv[p].y : (t == 2) ? zv[p].z : zv[p].w;
                a0[p] += zc * wA;
                a1[p] += zc * wB;
            }
        }
    }
    float bA = b1[lane], bB = b1[lane + 64];
    float wvA = w2[lane], wvB = w2[lane + 64];
    float s[NP];
#pragma unroll
    for (int p = 0; p < NP; p++)
        s[p] = tanhf(a0[p] + bA) * wvA + tanhf(a1[p] + bB) * wvB;
#pragma unroll
    for (int off = 1; off < 64; off <<= 1) {
#pragma unroll
        for (int p = 0; p < NP; p++) s[p] += __shfl_xor(s[p], off);
    }
    float m = fmaxf(fmaxf(s[0], s[1]), fmaxf(s[2], s[3]));
    float e0 = __expf(s[0] - m), e1 = __expf(s[1] - m),
          e2 = __expf(s[2] - m), e3 = __expf(s[3] - m);
    float r = 1.0f / (e0 + e1 + e2 + e3);
    float be[NP] = {e0 * r, e1 * r, e2 * r, e3 * r};

    float4 o;
    o.x = be[0] * zf[0].x + be[1] * zf[1].x + be[2] * zf[2].x + be[3] * zf[3].x;
    o.y = be[0] * zf[0].y + be[1] * zf[1].y + be[2] * zf[2].y + be[3] * zf[3].y;
    o.z = be[0] * zf[0].z + be[1] * zf[1].z + be[2] * zf[2].z + be[3] * zf[3].z;
    o.w = be[0] * zf[0].w + be[1] * zf[1].w + be[2] * zf[2].w + be[3] * zf[3].w;
    *(float4*)(out + (size_t)n * DD + lane * 4) = o;
}

extern "C" void kernel_launch(void* const* d_in, const int* in_sizes, int n_in,
                              void* d_out, int out_size, void* d_ws, size_t ws_size,
                              hipStream_t stream) {
    const float* x     = (const float*)d_in[0];
    const int*   edges = (const int*)d_in[1];   // [4][2][800000]
    const float* Ws    = (const float*)d_in[2]; // [4][256][256]
    const float* bs    = (const float*)d_in[3]; // [4][256]
    const float* w1    = (const float*)d_in[4]; // [256][128]
    const float* b1    = (const float*)d_in[5]; // [128]
    const float* w2    = (const float*)d_in[6]; // [128]
    float* out = (float*)d_out;

    char* ws = (char*)d_ws;
    int*      degi = (int*)(ws);                     // 800 KB (+cnt at +800000)
    int*      cnt  = (int*)(ws + 800000);            // 4 paths x 128 B stride
    float*    dinv = (float*)(ws + (1 << 20));       // 800 KB
    int*      offs = (int*)(ws + (2 << 20));         // 800 KB
    int*      curs = (int*)(ws + (3 << 20));         // 800 KB
    int*      srcs = (int*)(ws + (4 << 20));         // 12.8 MB
    _Float16* Wt   = (_Float16*)(ws + (17 << 20));   // 512 KB
    _Float16* xh   = (_Float16*)(ws + (18 << 20));   // 25.6 MB (MPAD rows)
    _Float16* xws  = (_Float16*)(ws + (44 << 20));   // 102.4 MB  -> total ~147 MB

    hipMemsetAsync(degi, 0, 800000 + 512, stream);

    k_cvt_x<<<(NN * DD / 8 + 255) / 256, 256, 0, stream>>>(x, xh);
    k_cvt_w<<<(NP * DD * DD / 8 + 255) / 256, 256, 0, stream>>>(Ws, Wt);

    k_deg  <<<(NP * NE + 255) / 256, 256, 0, stream>>>(edges, degi);
    k_dinv <<<(NP * NN + 255) / 256, 256, 0, stream>>>(degi, dinv);
    dim3 agrid((NN + 255) / 256, NP);
    k_alloc<<<agrid, 256, 0, stream>>>(degi, cnt, offs, curs);
    k_fill <<<(NP * NE + 255) / 256, 256, 0, stream>>>(edges, curs, srcs);

    dim3 ggrid(MPAD / 64, NP);
    k_gemm_mfma<<<ggrid, 256, 0, stream>>>(xh, Wt, dinv, xws);

    k_fused<<<NN / 4, 256, 0, stream>>>((const __half*)xws, dinv, offs, curs, srcs,
                                        bs, w1, b1, w2, out);
}

// Round 5
// 1022.034 us; speedup vs baseline: 11.4386x; 1.1527x over previous
//
#include <hip/hip_runtime.h>
#include <hip/hip_fp16.h>
#include <cstdint>
#include <cstddef>

#define NN 50000      // nodes
#define NE 800000     // edges per path
#define NP 4          // metapaths
#define DD 256        // d_in = d_out
#define HH 128        // attention hidden
#define MPAD 50048    // NN rounded up to 64 (782*64)

typedef _Float16 f16x8 __attribute__((ext_vector_type(8)));
typedef float f32x4 __attribute__((ext_vector_type(4)));

// ---------------- x (fp32) -> xh (f16), 8 elems/thread ----------------------
__global__ __launch_bounds__(256) void k_cvt_x(const float* __restrict__ x,
                                               _Float16* __restrict__ xh) {
    int i = blockIdx.x * 256 + threadIdx.x;     // one octet of elements
    if (i >= NN * DD / 8) return;
    const float4* src = (const float4*)x + (size_t)i * 2;
    float4 v0 = src[0], v1 = src[1];
    f16x8 o;
    o[0] = (_Float16)v0.x; o[1] = (_Float16)v0.y; o[2] = (_Float16)v0.z; o[3] = (_Float16)v0.w;
    o[4] = (_Float16)v1.x; o[5] = (_Float16)v1.y; o[6] = (_Float16)v1.z; o[7] = (_Float16)v1.w;
    *((f16x8*)xh + i) = o;
}

// ---------------- Ws [p][k][n] fp32 -> Wt [p][n][k] f16 ---------------------
__global__ __launch_bounds__(256) void k_cvt_w(const float* __restrict__ Ws,
                                               _Float16* __restrict__ Wt) {
    int i = blockIdx.x * 256 + threadIdx.x;     // (p, n, k-octet)
    if (i >= NP * DD * DD / 8) return;
    int p   = i / (DD * DD / 8);
    int rem = i - p * (DD * DD / 8);
    int n   = rem >> 5;
    int k8  = (rem & 31) * 8;
    const float* wp = Ws + (size_t)p * DD * DD;
    f16x8 o;
#pragma unroll
    for (int t = 0; t < 8; t++) o[t] = (_Float16)wp[(size_t)(k8 + t) * DD + n];
    *((f16x8*)(Wt + (size_t)p * DD * DD + (size_t)n * DD + k8)) = o;
}

// ---------------- w1 [256 k][128 n] fp32 -> w1t [128 n][256 k] f16 ----------
__global__ __launch_bounds__(256) void k_cvt_w1(const float* __restrict__ w1,
                                                _Float16* __restrict__ w1t) {
    int i = blockIdx.x * 256 + threadIdx.x;     // (n, k-octet): 128*32
    if (i >= HH * DD / 8) return;
    int n  = i >> 5;
    int k8 = (i & 31) * 8;
    f16x8 o;
#pragma unroll
    for (int t = 0; t < 8; t++) o[t] = (_Float16)w1[(size_t)(k8 + t) * HH + n];
    *((f16x8*)(w1t + (size_t)n * DD + k8)) = o;
}

// ---------------- in-degree count (int, by dst) ----------------
__global__ __launch_bounds__(256) void k_deg(const int* __restrict__ edges,
                                             int* __restrict__ degi) {
    int i = blockIdx.x * 256 + threadIdx.x;
    if (i >= NP * NE) return;
    int p = i / NE;
    int e = i - p * NE;
    int dst = edges[(size_t)p * 2 * NE + NE + e];
    atomicAdd(&degi[p * NN + dst], 1);
}

// dinv = rsqrt(deg + 1)   (+1 = self loop)
__global__ __launch_bounds__(256) void k_dinv(const int* __restrict__ degi,
                                              float* __restrict__ dinv) {
    int i = blockIdx.x * 256 + threadIdx.x;
    if (i >= NP * NN) return;
    dinv[i] = rsqrtf((float)degi[i] + 1.0f);
}

// CSR range allocation via wave-aggregated atomics (one atomic per wave).
__global__ __launch_bounds__(256) void k_alloc(const int* __restrict__ degi,
                                               int* __restrict__ cnt,   // stride 32 ints per path
                                               int* __restrict__ offs,
                                               int* __restrict__ curs) {
    const int p = blockIdx.y;
    const int i = blockIdx.x * 256 + threadIdx.x;
    const int lane = threadIdx.x & 63;
    const bool active = i < NN;
    int d = active ? degi[p * NN + i] : 0;
    int incl = d;
#pragma unroll
    for (int off = 1; off < 64; off <<= 1) {
        int v = __shfl_up(incl, off);
        if (lane >= off) incl += v;
    }
    int total = __shfl(incl, 63);
    int base = 0;
    if (lane == 0) base = atomicAdd(&cnt[p * 32], total);
    base = __shfl(base, 0);
    if (active) {
        int o = base + incl - d;
        offs[p * NN + i] = o;
        curs[p * NN + i] = o;
    }
}

// fill srcs grouped by dst; after this, curs[i] == offs[i] + degi[i]
__global__ __launch_bounds__(256) void k_fill(const int* __restrict__ edges,
                                              int* __restrict__ curs,
                                              int* __restrict__ srcs) {
    int i = blockIdx.x * 256 + threadIdx.x;
    if (i >= NP * NE) return;
    int p = i / NE;
    int e = i - p * NE;
    int src = edges[(size_t)p * 2 * NE + e];
    int dst = edges[(size_t)p * 2 * NE + NE + e];
    int pos = atomicAdd(&curs[p * NN + dst], 1);
    srcs[(size_t)p * NE + pos] = src;
}

// ---------------- f16 MFMA GEMM: xws = f16(dinv * (xh @ W)) -----------------
__global__ __launch_bounds__(256) void k_gemm_mfma(const _Float16* __restrict__ xh,  // [MPAD][256]
                                                   const _Float16* __restrict__ Wt,  // [NP][256 n][256 k]
                                                   const float* __restrict__ dinv,   // [NP][NN]
                                                   _Float16* __restrict__ xws) {     // [NP][NN][256]
    const int p    = blockIdx.y;
    const int wv   = threadIdx.x >> 6;
    const int lane = threadIdx.x & 63;
    const int m_base = blockIdx.x * 64;
    const int n0   = wv * 64;
    const int mr   = lane & 15;
    const int quad = lane >> 4;

    const _Float16* ap = xh + (size_t)(m_base + mr) * DD + quad * 8;
    const _Float16* bp = Wt + (size_t)p * DD * DD + (size_t)(n0 + mr) * DD + quad * 8;
    const float* dv = dinv + (size_t)p * NN;
    _Float16* cp = xws + (size_t)p * NN * DD;

    f32x4 acc[4][4] = {};   // [m-tile][n-tile]
    for (int k0 = 0; k0 < DD; k0 += 32) {
        f16x8 a[4], b[4];
#pragma unroll
        for (int i = 0; i < 4; i++) a[i] = *(const f16x8*)(ap + (size_t)i * 16 * DD + k0);
#pragma unroll
        for (int j = 0; j < 4; j++) b[j] = *(const f16x8*)(bp + (size_t)j * 16 * DD + k0);
#pragma unroll
        for (int i = 0; i < 4; i++)
#pragma unroll
            for (int j = 0; j < 4; j++)
                acc[i][j] = __builtin_amdgcn_mfma_f32_16x16x32_f16(a[i], b[j], acc[i][j], 0, 0, 0);
    }
#pragma unroll
    for (int i = 0; i < 4; i++) {
#pragma unroll
        for (int r = 0; r < 4; r++) {
            int row = m_base + i * 16 + quad * 4 + r;
            if (row < NN) {
                float d = dv[row];
#pragma unroll
                for (int j = 0; j < 4; j++)
                    cp[(size_t)row * DD + n0 + j * 16 + mr] = (_Float16)(d * acc[i][j][r]);
            }
        }
    }
}

// ---------------- fused gather + bias + MFMA semantic attention -------------
// 256 threads = 4 waves; block handles 16 nodes (64 z-rows in LDS).
// All LDS traffic is wave-local (wave w owns rows [w*16, w*16+16)) -> no barriers.
__global__ __launch_bounds__(256) void k_fused(const _Float16* __restrict__ xws, // [NP][NN][256] dinv-scaled f16
                                               const float* __restrict__ dinv,   // [NP][NN]
                                               const int* __restrict__ offs,     // [NP][NN]
                                               const int* __restrict__ ends,     // [NP][NN]
                                               const int* __restrict__ srcs,     // [NP][NE]
                                               const float* __restrict__ bs,     // [NP][256]
                                               const _Float16* __restrict__ w1t, // [128 n][256 k] f16
                                               const float* __restrict__ b1,     // [128]
                                               const float* __restrict__ w2,     // [128]
                                               float* __restrict__ out) {        // [NN][256]
    const int w    = threadIdx.x >> 6;
    const int lane = threadIdx.x & 63;
    const int quad = lane >> 4, mr = lane & 15;
    const int half = lane >> 5, hl = lane & 31;

    // row stride 264 halves = 528 B: keeps f16x8 accesses 16B-aligned,
    // A-frag reads <=2-way bank aliased (free).
    __shared__ __align__(16) _Float16 zs[64][264];

    union U { f16x8 v; int i4[4]; };

    // ---- gather: z[row] = dinv*(self + sum_src xws[src]) + bias, row=(node,path)
    // lanes 0-31 take even edges, 32-63 odd edges; 16B loads cover the 512B row.
#pragma unroll 1
    for (int q = 0; q < 4; q++) {
        const int n = blockIdx.x * 16 + w * 4 + q;
#pragma unroll 1
        for (int p = 0; p < NP; p++) {
            const _Float16* xp = xws + (size_t)p * NN * DD;
            const int* sp = srcs + (size_t)p * NE;
            U acc;
#pragma unroll
            for (int t = 0; t < 4; t++) acc.i4[t] = 0;
            if (half == 0)
                acc.v = *(const f16x8*)(xp + (size_t)n * DD + hl * 8);  // self loop
            int k  = offs[p * NN + n];
            int ke = ends[p * NN + n];
            for (; k + 4 <= ke; k += 4) {
                int s0 = sp[k + half];
                int s1 = sp[k + 2 + half];
                f16x8 v0 = *(const f16x8*)(xp + (size_t)s0 * DD + hl * 8);
                f16x8 v1 = *(const f16x8*)(xp + (size_t)s1 * DD + hl * 8);
                acc.v += v0 + v1;
            }
            for (; k + 2 <= ke; k += 2) {
                int s0 = sp[k + half];
                acc.v += *(const f16x8*)(xp + (size_t)s0 * DD + hl * 8);
            }
            if (k < ke && half == 0)
                acc.v += *(const f16x8*)(xp + (size_t)sp[k] * DD + hl * 8);
            // combine even/odd halves
            U other;
#pragma unroll
            for (int t = 0; t < 4; t++) other.i4[t] = __shfl_xor(acc.i4[t], 32);
            acc.v += other.v;
            if (half == 0) {
                float dvv = dinv[p * NN + n];
                int row = w * 16 + q * 4 + p;
                f16x8 zo;
#pragma unroll
                for (int t = 0; t < 8; t++)
                    zo[t] = (_Float16)(dvv * (float)acc.v[t] + bs[p * DD + hl * 8 + t]);
                *(f16x8*)&zs[row][hl * 8] = zo;
            }
        }
    }

    // ---- attention MFMA: H(16x128) = Z_rows(16x256) @ w1t(128x256)^T per wave
    f32x4 acch[8] = {};
    for (int k0 = 0; k0 < DD; k0 += 32) {
        f16x8 a = *(const f16x8*)&zs[w * 16 + mr][k0 + quad * 8];
#pragma unroll
        for (int j = 0; j < 8; j++) {
            f16x8 b = *(const f16x8*)(w1t + (size_t)(j * 16 + mr) * DD + k0 + quad * 8);
            acch[j] = __builtin_amdgcn_mfma_f32_16x16x32_f16(a, b, acch[j], 0, 0, 0);
        }
    }

    // ---- scores: s[path] = sum_col tanh(h + b1[col]) * w2[col]
    // C layout: col = j*16+mr, row = quad*4 + reg; row = local_node*4 + path,
    // so quad owns node (w*4+quad), reg indexes its 4 paths.
    float part[4] = {};
#pragma unroll
    for (int j = 0; j < 8; j++) {
        int col = j * 16 + mr;
        float bb = b1[col], ww = w2[col];
#pragma unroll
        for (int r = 0; r < 4; r++)
            part[r] += tanhf(acch[j][r] + bb) * ww;
    }
#pragma unroll
    for (int off = 1; off < 16; off <<= 1) {
#pragma unroll
        for (int r = 0; r < 4; r++) part[r] += __shfl_xor(part[r], off);
    }
    // softmax over 4 paths (redundant across the 16 lanes of the quad)
    float m = fmaxf(fmaxf(part[0], part[1]), fmaxf(part[2], part[3]));
    float e0 = __expf(part[0] - m), e1 = __expf(part[1] - m),
          e2 = __expf(part[2] - m), e3 = __expf(part[3] - m);
    float rr = 1.0f / (e0 + e1 + e2 + e3);
    float be[4] = {e0 * rr, e1 * rr, e2 * rr, e3 * rr};

    // ---- combine: lane handles node (w*4+quad), cols [mr*16, mr*16+16)
    const int n  = blockIdx.x * 16 + w * 4 + quad;
    const int rb = w * 16 + quad * 4;
    float o[16] = {};
#pragma unroll
    for (int p = 0; p < 4; p++) {
        f16x8 z0 = *(const f16x8*)&zs[rb + p][mr * 16];
        f16x8 z1 = *(const f16x8*)&zs[rb + p][mr * 16 + 8];
#pragma unroll
        for (int t = 0; t < 8; t++) {
            o[t]     += be[p] * (float)z0[t];
            o[t + 8] += be[p] * (float)z1[t];
        }
    }
#pragma unroll
    for (int t = 0; t < 16; t += 4)
        *(float4*)(out + (size_t)n * DD + mr * 16 + t) =
            make_float4(o[t], o[t + 1], o[t + 2], o[t + 3]);
}

extern "C" void kernel_launch(void* const* d_in, const int* in_sizes, int n_in,
                              void* d_out, int out_size, void* d_ws, size_t ws_size,
                              hipStream_t stream) {
    const float* x     = (const float*)d_in[0];
    const int*   edges = (const int*)d_in[1];   // [4][2][800000]
    const float* Ws    = (const float*)d_in[2]; // [4][256][256]
    const float* bs    = (const float*)d_in[3]; // [4][256]
    const float* w1    = (const float*)d_in[4]; // [256][128]
    const float* b1    = (const float*)d_in[5]; // [128]
    const float* w2    = (const float*)d_in[6]; // [128]
    float* out = (float*)d_out;

    char* ws = (char*)d_ws;
    int*      degi = (int*)(ws);                     // 800 KB (+cnt at +800000)
    int*      cnt  = (int*)(ws + 800000);            // 4 paths x 128 B stride
    float*    dinv = (float*)(ws + (1 << 20));       // 800 KB
    int*      offs = (int*)(ws + (2 << 20));         // 800 KB
    int*      curs = (int*)(ws + (3 << 20));         // 800 KB
    int*      srcs = (int*)(ws + (4 << 20));         // 12.8 MB
    _Float16* Wt   = (_Float16*)(ws + (17 << 20));   // 512 KB
    _Float16* w1t  = (_Float16*)(ws + (17 << 20) + (1 << 19)); // 64 KB
    _Float16* xh   = (_Float16*)(ws + (18 << 20));   // 25.6 MB (MPAD rows)
    _Float16* xws  = (_Float16*)(ws + (44 << 20));   // 102.4 MB  -> total ~147 MB

    hipMemsetAsync(degi, 0, 800000 + 512, stream);

    k_cvt_x <<<(NN * DD / 8 + 255) / 256, 256, 0, stream>>>(x, xh);
    k_cvt_w <<<(NP * DD * DD / 8 + 255) / 256, 256, 0, stream>>>(Ws, Wt);
    k_cvt_w1<<<(HH * DD / 8 + 255) / 256, 256, 0, stream>>>(w1, w1t);

    k_deg  <<<(NP * NE + 255) / 256, 256, 0, stream>>>(edges, degi);
    k_dinv <<<(NP * NN + 255) / 256, 256, 0, stream>>>(degi, dinv);
    dim3 agrid((NN + 255) / 256, NP);
    k_alloc<<<agrid, 256, 0, stream>>>(degi, cnt, offs, curs);
    k_fill <<<(NP * NE + 255) / 256, 256, 0, stream>>>(edges, curs, srcs);

    dim3 ggrid(MPAD / 64, NP);
    k_gemm_mfma<<<ggrid, 256, 0, stream>>>(xh, Wt, dinv, xws);

    k_fused<<<NN / 16, 256, 0, stream>>>(xws, dinv, offs, curs, srcs,
                                         bs, w1t, b1, w2, out);
}

// Round 6
// 902.680 us; speedup vs baseline: 12.9510x; 1.1322x over previous
//
#include <hip/hip_runtime.h>
#include <hip/hip_fp16.h>
#include <cstdint>
#include <cstddef>

#define NN 50000      // nodes
#define NE 800000     // edges per path
#define NP 4          // metapaths
#define DD 256        // d_in = d_out
#define HH 128        // attention hidden
#define MPAD 50048    // NN rounded up to 64 (782*64)

typedef _Float16 f16x8 __attribute__((ext_vector_type(8)));
typedef float f32x4 __attribute__((ext_vector_type(4)));

#define X_OCT (NN * DD / 8)        // 1,600,000
#define W_OCT (NP * DD * DD / 8)   // 32,768
#define W1_OCT (HH * DD / 8)       // 4,096

// ---------------- fused converts: x->f16, Ws->Wt[n][k] f16, w1->w1t[n][k] f16
__global__ __launch_bounds__(256) void k_cvt(const float* __restrict__ x,
                                             const float* __restrict__ Ws,
                                             const float* __restrict__ w1,
                                             _Float16* __restrict__ xh,
                                             _Float16* __restrict__ Wt,
                                             _Float16* __restrict__ w1t) {
    int i = blockIdx.x * 256 + threadIdx.x;
    if (i < X_OCT) {
        const float4* src = (const float4*)x + (size_t)i * 2;
        float4 v0 = src[0], v1 = src[1];
        f16x8 o;
        o[0] = (_Float16)v0.x; o[1] = (_Float16)v0.y; o[2] = (_Float16)v0.z; o[3] = (_Float16)v0.w;
        o[4] = (_Float16)v1.x; o[5] = (_Float16)v1.y; o[6] = (_Float16)v1.z; o[7] = (_Float16)v1.w;
        *((f16x8*)xh + i) = o;
    } else if (i < X_OCT + W_OCT) {
        int j = i - X_OCT;                 // (p, n, k-octet)
        int p   = j / (DD * DD / 8);
        int rem = j - p * (DD * DD / 8);
        int n   = rem >> 5;
        int k8  = (rem & 31) * 8;
        const float* wp = Ws + (size_t)p * DD * DD;
        f16x8 o;
#pragma unroll
        for (int t = 0; t < 8; t++) o[t] = (_Float16)wp[(size_t)(k8 + t) * DD + n];
        *((f16x8*)(Wt + (size_t)p * DD * DD + (size_t)n * DD + k8)) = o;
    } else if (i < X_OCT + W_OCT + W1_OCT) {
        int j = i - X_OCT - W_OCT;         // (n, k-octet)
        int n  = j >> 5;
        int k8 = (j & 31) * 8;
        f16x8 o;
#pragma unroll
        for (int t = 0; t < 8; t++) o[t] = (_Float16)w1[(size_t)(k8 + t) * HH + n];
        *((f16x8*)(w1t + (size_t)n * DD + k8)) = o;
    }
}

// ---------------- in-degree count (int, by dst) ----------------
__global__ __launch_bounds__(256) void k_deg(const int* __restrict__ edges,
                                             int* __restrict__ degi) {
    int i = blockIdx.x * 256 + threadIdx.x;
    if (i >= NP * NE) return;
    int p = i / NE;
    int e = i - p * NE;
    int dst = edges[(size_t)p * 2 * NE + NE + e];
    atomicAdd(&degi[p * NN + dst], 1);
}

// CSR range allocation via wave-aggregated atomics + dinv computation fused.
__global__ __launch_bounds__(256) void k_alloc(const int* __restrict__ degi,
                                               int* __restrict__ cnt,   // stride 32 ints per path
                                               int* __restrict__ offs,
                                               int* __restrict__ curs,
                                               float* __restrict__ dinv) {
    const int p = blockIdx.y;
    const int i = blockIdx.x * 256 + threadIdx.x;
    const int lane = threadIdx.x & 63;
    const bool active = i < NN;
    int d = active ? degi[p * NN + i] : 0;
    int incl = d;
#pragma unroll
    for (int off = 1; off < 64; off <<= 1) {
        int v = __shfl_up(incl, off);
        if (lane >= off) incl += v;
    }
    int total = __shfl(incl, 63);
    int base = 0;
    if (lane == 0) base = atomicAdd(&cnt[p * 32], total);
    base = __shfl(base, 0);
    if (active) {
        int o = base + incl - d;
        offs[p * NN + i] = o;
        curs[p * NN + i] = o;
        dinv[p * NN + i] = rsqrtf((float)d + 1.0f);
    }
}

// fill srcs grouped by dst; after this, curs[i] == offs[i] + degi[i]
__global__ __launch_bounds__(256) void k_fill(const int* __restrict__ edges,
                                              int* __restrict__ curs,
                                              int* __restrict__ srcs) {
    int i = blockIdx.x * 256 + threadIdx.x;
    if (i >= NP * NE) return;
    int p = i / NE;
    int e = i - p * NE;
    int src = edges[(size_t)p * 2 * NE + e];
    int dst = edges[(size_t)p * 2 * NE + NE + e];
    int pos = atomicAdd(&curs[p * NN + dst], 1);
    srcs[(size_t)p * NE + pos] = src;
}

// ---------------- f16 MFMA GEMM: xws = f16(dinv * (xh @ W)) -----------------
__global__ __launch_bounds__(256) void k_gemm_mfma(const _Float16* __restrict__ xh,  // [MPAD][256]
                                                   const _Float16* __restrict__ Wt,  // [NP][256 n][256 k]
                                                   const float* __restrict__ dinv,   // [NP][NN]
                                                   _Float16* __restrict__ xws) {     // [NP][NN][256]
    const int p    = blockIdx.y;
    const int wv   = threadIdx.x >> 6;
    const int lane = threadIdx.x & 63;
    const int m_base = blockIdx.x * 64;
    const int n0   = wv * 64;
    const int mr   = lane & 15;
    const int quad = lane >> 4;

    const _Float16* ap = xh + (size_t)(m_base + mr) * DD + quad * 8;
    const _Float16* bp = Wt + (size_t)p * DD * DD + (size_t)(n0 + mr) * DD + quad * 8;
    const float* dv = dinv + (size_t)p * NN;
    _Float16* cp = xws + (size_t)p * NN * DD;

    f32x4 acc[4][4] = {};   // [m-tile][n-tile]
    for (int k0 = 0; k0 < DD; k0 += 32) {
        f16x8 a[4], b[4];
#pragma unroll
        for (int i = 0; i < 4; i++) a[i] = *(const f16x8*)(ap + (size_t)i * 16 * DD + k0);
#pragma unroll
        for (int j = 0; j < 4; j++) b[j] = *(const f16x8*)(bp + (size_t)j * 16 * DD + k0);
#pragma unroll
        for (int i = 0; i < 4; i++)
#pragma unroll
            for (int j = 0; j < 4; j++)
                acc[i][j] = __builtin_amdgcn_mfma_f32_16x16x32_f16(a[i], b[j], acc[i][j], 0, 0, 0);
    }
#pragma unroll
    for (int i = 0; i < 4; i++) {
#pragma unroll
        for (int r = 0; r < 4; r++) {
            int row = m_base + i * 16 + quad * 4 + r;
            if (row < NN) {
                float d = dv[row];
#pragma unroll
                for (int j = 0; j < 4; j++)
                    cp[(size_t)row * DD + n0 + j * 16 + mr] = (_Float16)(d * acc[i][j][r]);
            }
        }
    }
}

// ---------------- fused gather + bias + MFMA semantic attention -------------
// 512 threads = 8 waves; block handles 16 nodes (64 z-rows in LDS, 33.8 KB).
// Gather: wave w owns nodes {2w, 2w+1} -> rows [w*8, w*8+8), wave-local.
// One barrier, then waves 0-3 do MFMA attention on 16 rows each.
// Occupancy: 4 blocks/CU (LDS-limited) x 8 waves = 32 waves/CU = 100%.
__global__ __launch_bounds__(512) void k_fused(const _Float16* __restrict__ xws, // [NP][NN][256] dinv-scaled f16
                                               const float* __restrict__ dinv,   // [NP][NN]
                                               const int* __restrict__ offs,     // [NP][NN]
                                               const int* __restrict__ ends,     // [NP][NN]
                                               const int* __restrict__ srcs,     // [NP][NE]
                                               const float* __restrict__ bs,     // [NP][256]
                                               const _Float16* __restrict__ w1t, // [128 n][256 k] f16
                                               const float* __restrict__ b1,     // [128]
                                               const float* __restrict__ w2,     // [128]
                                               float* __restrict__ out) {        // [NN][256]
    const int w    = threadIdx.x >> 6;   // 0..7
    const int lane = threadIdx.x & 63;
    const int quad = lane >> 4, mr = lane & 15;
    const int half = lane >> 5, hl = lane & 31;

    // row stride 264 halves = 528 B keeps f16x8 accesses 16B-aligned.
    __shared__ __align__(16) _Float16 zs[64][264];

    union U { f16x8 v; int i4[4]; };

    // ---- gather: z[row] = dinv*(self + sum_src xws[src]) + bias, row=(node,path)
    // lanes 0-31 take even edges, 32-63 odd edges; 8-edge unroll = 4 loads in flight.
#pragma unroll 1
    for (int q = 0; q < 2; q++) {
        const int n = blockIdx.x * 16 + w * 2 + q;
#pragma unroll 1
        for (int p = 0; p < NP; p++) {
            const _Float16* xp = xws + (size_t)p * NN * DD;
            const int* sp = srcs + (size_t)p * NE;
            U acc;
#pragma unroll
            for (int t = 0; t < 4; t++) acc.i4[t] = 0;
            if (half == 0)
                acc.v = *(const f16x8*)(xp + (size_t)n * DD + hl * 8);  // self loop
            int k  = offs[p * NN + n];
            int ke = ends[p * NN + n];
            for (; k + 8 <= ke; k += 8) {
                int s0 = sp[k + half];
                int s1 = sp[k + 2 + half];
                int s2 = sp[k + 4 + half];
                int s3 = sp[k + 6 + half];
                f16x8 v0 = *(const f16x8*)(xp + (size_t)s0 * DD + hl * 8);
                f16x8 v1 = *(const f16x8*)(xp + (size_t)s1 * DD + hl * 8);
                f16x8 v2 = *(const f16x8*)(xp + (size_t)s2 * DD + hl * 8);
                f16x8 v3 = *(const f16x8*)(xp + (size_t)s3 * DD + hl * 8);
                acc.v += (v0 + v1) + (v2 + v3);
            }
            for (; k + 2 <= ke; k += 2) {
                int s0 = sp[k + half];
                acc.v += *(const f16x8*)(xp + (size_t)s0 * DD + hl * 8);
            }
            if (k < ke && half == 0)
                acc.v += *(const f16x8*)(xp + (size_t)sp[k] * DD + hl * 8);
            // combine even/odd halves
            U other;
#pragma unroll
            for (int t = 0; t < 4; t++) other.i4[t] = __shfl_xor(acc.i4[t], 32);
            acc.v += other.v;
            if (half == 0) {
                float dvv = dinv[p * NN + n];
                int row = (w * 2 + q) * 4 + p;
                f16x8 zo;
#pragma unroll
                for (int t = 0; t < 8; t++)
                    zo[t] = (_Float16)(dvv * (float)acc.v[t] + bs[p * DD + hl * 8 + t]);
                *(f16x8*)&zs[row][hl * 8] = zo;
            }
        }
    }

    __syncthreads();
    if (w >= 4) return;   // attention/combine handled by waves 0-3 (16 rows each)

    // ---- attention MFMA: H(16x128) = Z_rows(16x256) @ w1t(128x256)^T per wave
    f32x4 acch[8] = {};
    for (int k0 = 0; k0 < DD; k0 += 32) {
        f16x8 a = *(const f16x8*)&zs[w * 16 + mr][k0 + quad * 8];
#pragma unroll
        for (int j = 0; j < 8; j++) {
            f16x8 b = *(const f16x8*)(w1t + (size_t)(j * 16 + mr) * DD + k0 + quad * 8);
            acch[j] = __builtin_amdgcn_mfma_f32_16x16x32_f16(a, b, acch[j], 0, 0, 0);
        }
    }

    // ---- scores: s[path] = sum_col tanh(h + b1[col]) * w2[col]
    // C layout: col = j*16+mr, row = quad*4 + reg; row = local_node*4 + path.
    float part[4] = {};
#pragma unroll
    for (int j = 0; j < 8; j++) {
        int col = j * 16 + mr;
        float bb = b1[col], ww = w2[col];
#pragma unroll
        for (int r = 0; r < 4; r++)
            part[r] += tanhf(acch[j][r] + bb) * ww;
    }
#pragma unroll
    for (int off = 1; off < 16; off <<= 1) {
#pragma unroll
        for (int r = 0; r < 4; r++) part[r] += __shfl_xor(part[r], off);
    }
    // softmax over 4 paths (redundant across the 16 lanes of the quad)
    float m = fmaxf(fmaxf(part[0], part[1]), fmaxf(part[2], part[3]));
    float e0 = __expf(part[0] - m), e1 = __expf(part[1] - m),
          e2 = __expf(part[2] - m), e3 = __expf(part[3] - m);
    float rr = 1.0f / (e0 + e1 + e2 + e3);
    float be[4] = {e0 * rr, e1 * rr, e2 * rr, e3 * rr};

    // ---- combine: lane handles node (w*4+quad), cols [mr*16, mr*16+16)
    const int n  = blockIdx.x * 16 + w * 4 + quad;
    const int rb = w * 16 + quad * 4;
    float o[16] = {};
#pragma unroll
    for (int p = 0; p < 4; p++) {
        f16x8 z0 = *(const f16x8*)&zs[rb + p][mr * 16];
        f16x8 z1 = *(const f16x8*)&zs[rb + p][mr * 16 + 8];
#pragma unroll
        for (int t = 0; t < 8; t++) {
            o[t]     += be[p] * (float)z0[t];
            o[t + 8] += be[p] * (float)z1[t];
        }
    }
#pragma unroll
    for (int t = 0; t < 16; t += 4)
        *(float4*)(out + (size_t)n * DD + mr * 16 + t) =
            make_float4(o[t], o[t + 1], o[t + 2], o[t + 3]);
}

extern "C" void kernel_launch(void* const* d_in, const int* in_sizes, int n_in,
                              void* d_out, int out_size, void* d_ws, size_t ws_size,
                              hipStream_t stream) {
    const float* x     = (const float*)d_in[0];
    const int*   edges = (const int*)d_in[1];   // [4][2][800000]
    const float* Ws    = (const float*)d_in[2]; // [4][256][256]
    const float* bs    = (const float*)d_in[3]; // [4][256]
    const float* w1    = (const float*)d_in[4]; // [256][128]
    const float* b1    = (const float*)d_in[5]; // [128]
    const float* w2    = (const float*)d_in[6]; // [128]
    float* out = (float*)d_out;

    char* ws = (char*)d_ws;
    int*      degi = (int*)(ws);                     // 800 KB (+cnt at +800000)
    int*      cnt  = (int*)(ws + 800000);            // 4 paths x 128 B stride
    float*    dinv = (float*)(ws + (1 << 20));       // 800 KB
    int*      offs = (int*)(ws + (2 << 20));         // 800 KB
    int*      curs = (int*)(ws + (3 << 20));         // 800 KB
    int*      srcs = (int*)(ws + (4 << 20));         // 12.8 MB
    _Float16* Wt   = (_Float16*)(ws + (17 << 20));   // 512 KB
    _Float16* w1t  = (_Float16*)(ws + (17 << 20) + (1 << 19)); // 64 KB
    _Float16* xh   = (_Float16*)(ws + (18 << 20));   // 25.6 MB (MPAD rows)
    _Float16* xws  = (_Float16*)(ws + (44 << 20));   // 102.4 MB  -> total ~147 MB

    hipMemsetAsync(degi, 0, 800000 + 512, stream);

    k_cvt<<<(X_OCT + W_OCT + W1_OCT + 255) / 256, 256, 0, stream>>>(
        x, Ws, w1, xh, Wt, w1t);

    k_deg  <<<(NP * NE + 255) / 256, 256, 0, stream>>>(edges, degi);
    dim3 agrid((NN + 255) / 256, NP);
    k_alloc<<<agrid, 256, 0, stream>>>(degi, cnt, offs, curs, dinv);
    k_fill <<<(NP * NE + 255) / 256, 256, 0, stream>>>(edges, curs, srcs);

    dim3 ggrid(MPAD / 64, NP);
    k_gemm_mfma<<<ggrid, 256, 0, stream>>>(xh, Wt, dinv, xws);

    k_fused<<<NN / 16, 512, 0, stream>>>(xws, dinv, offs, curs, srcs,
                                         bs, w1t, b1, w2, out);
}

// Round 7
// 900.901 us; speedup vs baseline: 12.9766x; 1.0020x over previous
//
#include <hip/hip_runtime.h>
#include <hip/hip_fp16.h>
#include <cstdint>
#include <cstddef>

#define NN 50000      // nodes
#define NE 800000     // edges per path
#define NP 4          // metapaths
#define DD 256        // d_in = d_out
#define HH 128        // attention hidden
#define MPAD 50048    // NN rounded up to 64 (782*64)

typedef _Float16 f16x8 __attribute__((ext_vector_type(8)));
typedef float f32x4 __attribute__((ext_vector_type(4)));

#define X_OCT (NN * DD / 8)        // 1,600,000
#define W_OCT (NP * DD * DD / 8)   // 32,768
#define W1_OCT (HH * DD / 8)       // 4,096
#define DEG_BLOCKS ((NP * NE + 255) / 256)                    // 12500
#define CVT_BLOCKS ((X_OCT + W_OCT + W1_OCT + 255) / 256)     // 6394
#define GEMM_BLOCKS ((MPAD / 64) * NP)                        // 3128
#define FILL_BLOCKS ((NP * NE + 255) / 256)                   // 12500

// ---------------- prep: degree-count atomics ∥ fp32->f16 converts -----------
// deg blocks first (atomic long pole starts immediately), cvt blocks overlap.
__global__ __launch_bounds__(256) void k_prep(const int* __restrict__ edges,
                                              int* __restrict__ degi,
                                              const float* __restrict__ x,
                                              const float* __restrict__ Ws,
                                              const float* __restrict__ w1,
                                              _Float16* __restrict__ xh,
                                              _Float16* __restrict__ Wt,
                                              _Float16* __restrict__ w1t) {
    const int bx = blockIdx.x;
    if (bx < DEG_BLOCKS) {
        int i = bx * 256 + threadIdx.x;
        if (i >= NP * NE) return;
        int p = i / NE;
        int e = i - p * NE;
        int dst = edges[(size_t)p * 2 * NE + NE + e];
        atomicAdd(&degi[p * NN + dst], 1);
        return;
    }
    int i = (bx - DEG_BLOCKS) * 256 + threadIdx.x;
    if (i < X_OCT) {
        const float4* src = (const float4*)x + (size_t)i * 2;
        float4 v0 = src[0], v1 = src[1];
        f16x8 o;
        o[0] = (_Float16)v0.x; o[1] = (_Float16)v0.y; o[2] = (_Float16)v0.z; o[3] = (_Float16)v0.w;
        o[4] = (_Float16)v1.x; o[5] = (_Float16)v1.y; o[6] = (_Float16)v1.z; o[7] = (_Float16)v1.w;
        *((f16x8*)xh + i) = o;
    } else if (i < X_OCT + W_OCT) {
        int j = i - X_OCT;                 // (p, n, k-octet)
        int p   = j / (DD * DD / 8);
        int rem = j - p * (DD * DD / 8);
        int n   = rem >> 5;
        int k8  = (rem & 31) * 8;
        const float* wp = Ws + (size_t)p * DD * DD;
        f16x8 o;
#pragma unroll
        for (int t = 0; t < 8; t++) o[t] = (_Float16)wp[(size_t)(k8 + t) * DD + n];
        *((f16x8*)(Wt + (size_t)p * DD * DD + (size_t)n * DD + k8)) = o;
    } else if (i < X_OCT + W_OCT + W1_OCT) {
        int j = i - X_OCT - W_OCT;         // (n, k-octet)
        int n  = j >> 5;
        int k8 = (j & 31) * 8;
        f16x8 o;
#pragma unroll
        for (int t = 0; t < 8; t++) o[t] = (_Float16)w1[(size_t)(k8 + t) * HH + n];
        *((f16x8*)(w1t + (size_t)n * DD + k8)) = o;
    }
}

// CSR range allocation via wave-aggregated atomics + dinv computation fused.
__global__ __launch_bounds__(256) void k_alloc(const int* __restrict__ degi,
                                               int* __restrict__ cnt,   // stride 32 ints per path
                                               int* __restrict__ offs,
                                               int* __restrict__ curs,
                                               float* __restrict__ dinv) {
    const int p = blockIdx.y;
    const int i = blockIdx.x * 256 + threadIdx.x;
    const int lane = threadIdx.x & 63;
    const bool active = i < NN;
    int d = active ? degi[p * NN + i] : 0;
    int incl = d;
#pragma unroll
    for (int off = 1; off < 64; off <<= 1) {
        int v = __shfl_up(incl, off);
        if (lane >= off) incl += v;
    }
    int total = __shfl(incl, 63);
    int base = 0;
    if (lane == 0) base = atomicAdd(&cnt[p * 32], total);
    base = __shfl(base, 0);
    if (active) {
        int o = base + incl - d;
        offs[p * NN + i] = o;
        curs[p * NN + i] = o;
        dinv[p * NN + i] = rsqrtf((float)d + 1.0f);
    }
}

// ---------------- mid: f16 MFMA GEMM ∥ CSR fill -----------------------------
// Both depend only on k_alloc outputs (dinv / curs). GEMM blocks first.
// GEMM: xws = f16(dinv * (xh @ W)); fill: srcs grouped by dst via atomics.
__global__ __launch_bounds__(256) void k_mid(const _Float16* __restrict__ xh,  // [MPAD][256]
                                             const _Float16* __restrict__ Wt,  // [NP][256 n][256 k]
                                             const float* __restrict__ dinv,   // [NP][NN]
                                             _Float16* __restrict__ xws,       // [NP][NN][256]
                                             const int* __restrict__ edges,
                                             int* __restrict__ curs,
                                             int* __restrict__ srcs) {
    const int bx = blockIdx.x;
    if (bx >= GEMM_BLOCKS) {
        // ---- fill part ----
        int i = (bx - GEMM_BLOCKS) * 256 + threadIdx.x;
        if (i >= NP * NE) return;
        int p = i / NE;
        int e = i - p * NE;
        int src = edges[(size_t)p * 2 * NE + e];
        int dst = edges[(size_t)p * 2 * NE + NE + e];
        int pos = atomicAdd(&curs[p * NN + dst], 1);
        srcs[(size_t)p * NE + pos] = src;
        return;
    }
    // ---- GEMM part ----
    const int p    = bx / (MPAD / 64);
    const int bm   = bx - p * (MPAD / 64);
    const int wv   = threadIdx.x >> 6;
    const int lane = threadIdx.x & 63;
    const int m_base = bm * 64;
    const int n0   = wv * 64;
    const int mr   = lane & 15;
    const int quad = lane >> 4;

    const _Float16* ap = xh + (size_t)(m_base + mr) * DD + quad * 8;
    const _Float16* bp = Wt + (size_t)p * DD * DD + (size_t)(n0 + mr) * DD + quad * 8;
    const float* dv = dinv + (size_t)p * NN;
    _Float16* cp = xws + (size_t)p * NN * DD;

    f32x4 acc[4][4] = {};   // [m-tile][n-tile]
    for (int k0 = 0; k0 < DD; k0 += 32) {
        f16x8 a[4], b[4];
#pragma unroll
        for (int i = 0; i < 4; i++) a[i] = *(const f16x8*)(ap + (size_t)i * 16 * DD + k0);
#pragma unroll
        for (int j = 0; j < 4; j++) b[j] = *(const f16x8*)(bp + (size_t)j * 16 * DD + k0);
#pragma unroll
        for (int i = 0; i < 4; i++)
#pragma unroll
            for (int j = 0; j < 4; j++)
                acc[i][j] = __builtin_amdgcn_mfma_f32_16x16x32_f16(a[i], b[j], acc[i][j], 0, 0, 0);
    }
#pragma unroll
    for (int i = 0; i < 4; i++) {
#pragma unroll
        for (int r = 0; r < 4; r++) {
            int row = m_base + i * 16 + quad * 4 + r;
            if (row < NN) {
                float d = dv[row];
#pragma unroll
                for (int j = 0; j < 4; j++)
                    cp[(size_t)row * DD + n0 + j * 16 + mr] = (_Float16)(d * acc[i][j][r]);
            }
        }
    }
}

// ---------------- fused gather + bias + MFMA semantic attention -------------
// 512 threads = 8 waves; block handles 16 nodes (64 z-rows in LDS, 33.8 KB).
// Gather: wave w owns nodes {2w, 2w+1} -> rows [w*8, w*8+8), wave-local.
// One barrier, then waves 0-3 do MFMA attention on 16 rows each.
__global__ __launch_bounds__(512) void k_fused(const _Float16* __restrict__ xws, // [NP][NN][256] dinv-scaled f16
                                               const float* __restrict__ dinv,   // [NP][NN]
                                               const int* __restrict__ offs,     // [NP][NN]
                                               const int* __restrict__ ends,     // [NP][NN]
                                               const int* __restrict__ srcs,     // [NP][NE]
                                               const float* __restrict__ bs,     // [NP][256]
                                               const _Float16* __restrict__ w1t, // [128 n][256 k] f16
                                               const float* __restrict__ b1,     // [128]
                                               const float* __restrict__ w2,     // [128]
                                               float* __restrict__ out) {        // [NN][256]
    const int w    = threadIdx.x >> 6;   // 0..7
    const int lane = threadIdx.x & 63;
    const int quad = lane >> 4, mr = lane & 15;
    const int half = lane >> 5, hl = lane & 31;

    // row stride 264 halves = 528 B keeps f16x8 accesses 16B-aligned.
    __shared__ __align__(16) _Float16 zs[64][264];

    union U { f16x8 v; int i4[4]; };

    // ---- gather: z[row] = dinv*(self + sum_src xws[src]) + bias, row=(node,path)
    // lanes 0-31 take even edges, 32-63 odd edges; 8-edge unroll = 4 loads in flight.
#pragma unroll 1
    for (int q = 0; q < 2; q++) {
        const int n = blockIdx.x * 16 + w * 2 + q;
#pragma unroll 1
        for (int p = 0; p < NP; p++) {
            const _Float16* xp = xws + (size_t)p * NN * DD;
            const int* sp = srcs + (size_t)p * NE;
            U acc;
#pragma unroll
            for (int t = 0; t < 4; t++) acc.i4[t] = 0;
            if (half == 0)
                acc.v = *(const f16x8*)(xp + (size_t)n * DD + hl * 8);  // self loop
            int k  = offs[p * NN + n];
            int ke = ends[p * NN + n];
            for (; k + 8 <= ke; k += 8) {
                int s0 = sp[k + half];
                int s1 = sp[k + 2 + half];
                int s2 = sp[k + 4 + half];
                int s3 = sp[k + 6 + half];
                f16x8 v0 = *(const f16x8*)(xp + (size_t)s0 * DD + hl * 8);
                f16x8 v1 = *(const f16x8*)(xp + (size_t)s1 * DD + hl * 8);
                f16x8 v2 = *(const f16x8*)(xp + (size_t)s2 * DD + hl * 8);
                f16x8 v3 = *(const f16x8*)(xp + (size_t)s3 * DD + hl * 8);
                acc.v += (v0 + v1) + (v2 + v3);
            }
            for (; k + 2 <= ke; k += 2) {
                int s0 = sp[k + half];
                acc.v += *(const f16x8*)(xp + (size_t)s0 * DD + hl * 8);
            }
            if (k < ke && half == 0)
                acc.v += *(const f16x8*)(xp + (size_t)sp[k] * DD + hl * 8);
            // combine even/odd halves
            U other;
#pragma unroll
            for (int t = 0; t < 4; t++) other.i4[t] = __shfl_xor(acc.i4[t], 32);
            acc.v += other.v;
            if (half == 0) {
                float dvv = dinv[p * NN + n];
                int row = (w * 2 + q) * 4 + p;
                f16x8 zo;
#pragma unroll
                for (int t = 0; t < 8; t++)
                    zo[t] = (_Float16)(dvv * (float)acc.v[t] + bs[p * DD + hl * 8 + t]);
                *(f16x8*)&zs[row][hl * 8] = zo;
            }
        }
    }

    __syncthreads();
    if (w >= 4) return;   // attention/combine handled by waves 0-3 (16 rows each)

    // ---- attention MFMA: H(16x128) = Z_rows(16x256) @ w1t(128x256)^T per wave
    f32x4 acch[8] = {};
    for (int k0 = 0; k0 < DD; k0 += 32) {
        f16x8 a = *(const f16x8*)&zs[w * 16 + mr][k0 + quad * 8];
#pragma unroll
        for (int j = 0; j < 8; j++) {
            f16x8 b = *(const f16x8*)(w1t + (size_t)(j * 16 + mr) * DD + k0 + quad * 8);
            acch[j] = __builtin_amdgcn_mfma_f32_16x16x32_f16(a, b, acch[j], 0, 0, 0);
        }
    }

    // ---- scores: s[path] = sum_col tanh(h + b1[col]) * w2[col]
    // C layout: col = j*16+mr, row = quad*4 + reg; row = local_node*4 + path.
    float part[4] = {};
#pragma unroll
    for (int j = 0; j < 8; j++) {
        int col = j * 16 + mr;
        float bb = b1[col], ww = w2[col];
#pragma unroll
        for (int r = 0; r < 4; r++)
            part[r] += tanhf(acch[j][r] + bb) * ww;
    }
#pragma unroll
    for (int off = 1; off < 16; off <<= 1) {
#pragma unroll
        for (int r = 0; r < 4; r++) part[r] += __shfl_xor(part[r], off);
    }
    // softmax over 4 paths (redundant across the 16 lanes of the quad)
    float m = fmaxf(fmaxf(part[0], part[1]), fmaxf(part[2], part[3]));
    float e0 = __expf(part[0] - m), e1 = __expf(part[1] - m),
          e2 = __expf(part[2] - m), e3 = __expf(part[3] - m);
    float rr = 1.0f / (e0 + e1 + e2 + e3);
    float be[4] = {e0 * rr, e1 * rr, e2 * rr, e3 * rr};

    // ---- combine: lane handles node (w*4+quad), cols [mr*16, mr*16+16)
    const int n  = blockIdx.x * 16 + w * 4 + quad;
    const int rb = w * 16 + quad * 4;
    float o[16] = {};
#pragma unroll
    for (int p = 0; p < 4; p++) {
        f16x8 z0 = *(const f16x8*)&zs[rb + p][mr * 16];
        f16x8 z1 = *(const f16x8*)&zs[rb + p][mr * 16 + 8];
#pragma unroll
        for (int t = 0; t < 8; t++) {
            o[t]     += be[p] * (float)z0[t];
            o[t + 8] += be[p] * (float)z1[t];
        }
    }
#pragma unroll
    for (int t = 0; t < 16; t += 4)
        *(float4*)(out + (size_t)n * DD + mr * 16 + t) =
            make_float4(o[t], o[t + 1], o[t + 2], o[t + 3]);
}

extern "C" void kernel_launch(void* const* d_in, const int* in_sizes, int n_in,
                              void* d_out, int out_size, void* d_ws, size_t ws_size,
                              hipStream_t stream) {
    const float* x     = (const float*)d_in[0];
    const int*   edges = (const int*)d_in[1];   // [4][2][800000]
    const float* Ws    = (const float*)d_in[2]; // [4][256][256]
    const float* bs    = (const float*)d_in[3]; // [4][256]
    const float* w1    = (const float*)d_in[4]; // [256][128]
    const float* b1    = (const float*)d_in[5]; // [128]
    const float* w2    = (const float*)d_in[6]; // [128]
    float* out = (float*)d_out;

    char* ws = (char*)d_ws;
    int*      degi = (int*)(ws);                     // 800 KB (+cnt at +800000)
    int*      cnt  = (int*)(ws + 800000);            // 4 paths x 128 B stride
    float*    dinv = (float*)(ws + (1 << 20));       // 800 KB
    int*      offs = (int*)(ws + (2 << 20));         // 800 KB
    int*      curs = (int*)(ws + (3 << 20));         // 800 KB
    int*      srcs = (int*)(ws + (4 << 20));         // 12.8 MB
    _Float16* Wt   = (_Float16*)(ws + (17 << 20));   // 512 KB
    _Float16* w1t  = (_Float16*)(ws + (17 << 20) + (1 << 19)); // 64 KB
    _Float16* xh   = (_Float16*)(ws + (18 << 20));   // 25.6 MB (MPAD rows)
    _Float16* xws  = (_Float16*)(ws + (44 << 20));   // 102.4 MB  -> total ~147 MB

    hipMemsetAsync(degi, 0, 800000 + 512, stream);

    k_prep<<<DEG_BLOCKS + CVT_BLOCKS, 256, 0, stream>>>(
        edges, degi, x, Ws, w1, xh, Wt, w1t);

    dim3 agrid((NN + 255) / 256, NP);
    k_alloc<<<agrid, 256, 0, stream>>>(degi, cnt, offs, curs, dinv);

    k_mid<<<GEMM_BLOCKS + FILL_BLOCKS, 256, 0, stream>>>(
        xh, Wt, dinv, xws, edges, curs, srcs);

    k_fused<<<NN / 16, 512, 0, stream>>>(xws, dinv, offs, curs, srcs,
                                         bs, w1t, b1, w2, out);
}

// Round 8
// 862.139 us; speedup vs baseline: 13.5600x; 1.0450x over previous
//
#include <hip/hip_runtime.h>
#include <hip/hip_fp16.h>
#include <cstdint>
#include <cstddef>

#define NN 50000      // nodes
#define NE 800000     // edges per path
#define NP 4          // metapaths
#define DD 256        // d_in = d_out
#define HH 128        // attention hidden
#define MPAD 50048    // NN rounded up to 64 (782*64)
#define PSTR 16       // padded counter stride (ints) = 64 B/line -> no line sharing

typedef _Float16 f16x8 __attribute__((ext_vector_type(8)));
typedef float f32x4 __attribute__((ext_vector_type(4)));

#define X_OCT (NN * DD / 8)        // 1,600,000
#define W_OCT (NP * DD * DD / 8)   // 32,768
#define W1_OCT (HH * DD / 8)       // 4,096
#define EDGE_BLOCKS (NE / 256)                                // 3125 (4 paths/thread)
#define CVT_BLOCKS ((X_OCT + W_OCT + W1_OCT + 255) / 256)     // 6394
#define GEMM_BLOCKS ((MPAD / 64) * NP)                        // 3128

// ---------------- prep: degree-count atomics ∥ fp32->f16 converts -----------
// deg blocks first; thread i counts edge i of ALL 4 paths (4 independent
// non-returning atomics in flight, padded counters -> no line contention).
__global__ __launch_bounds__(256) void k_prep(const int* __restrict__ edges,
                                              int* __restrict__ degi,   // [NP*NN*PSTR]
                                              const float* __restrict__ x,
                                              const float* __restrict__ Ws,
                                              const float* __restrict__ w1,
                                              _Float16* __restrict__ xh,
                                              _Float16* __restrict__ Wt,
                                              _Float16* __restrict__ w1t) {
    const int bx = blockIdx.x;
    if (bx < EDGE_BLOCKS) {
        int i = bx * 256 + threadIdx.x;   // edge id within path
#pragma unroll
        for (int p = 0; p < NP; p++) {
            int dst = edges[(size_t)p * 2 * NE + NE + i];
            atomicAdd(&degi[(p * NN + dst) * PSTR], 1);
        }
        return;
    }
    int i = (bx - EDGE_BLOCKS) * 256 + threadIdx.x;
    if (i < X_OCT) {
        const float4* src = (const float4*)x + (size_t)i * 2;
        float4 v0 = src[0], v1 = src[1];
        f16x8 o;
        o[0] = (_Float16)v0.x; o[1] = (_Float16)v0.y; o[2] = (_Float16)v0.z; o[3] = (_Float16)v0.w;
        o[4] = (_Float16)v1.x; o[5] = (_Float16)v1.y; o[6] = (_Float16)v1.z; o[7] = (_Float16)v1.w;
        *((f16x8*)xh + i) = o;
    } else if (i < X_OCT + W_OCT) {
        int j = i - X_OCT;                 // (p, n, k-octet)
        int p   = j / (DD * DD / 8);
        int rem = j - p * (DD * DD / 8);
        int n   = rem >> 5;
        int k8  = (rem & 31) * 8;
        const float* wp = Ws + (size_t)p * DD * DD;
        f16x8 o;
#pragma unroll
        for (int t = 0; t < 8; t++) o[t] = (_Float16)wp[(size_t)(k8 + t) * DD + n];
        *((f16x8*)(Wt + (size_t)p * DD * DD + (size_t)n * DD + k8)) = o;
    } else if (i < X_OCT + W_OCT + W1_OCT) {
        int j = i - X_OCT - W_OCT;         // (n, k-octet)
        int n  = j >> 5;
        int k8 = (j & 31) * 8;
        f16x8 o;
#pragma unroll
        for (int t = 0; t < 8; t++) o[t] = (_Float16)w1[(size_t)(k8 + t) * HH + n];
        *((f16x8*)(w1t + (size_t)n * DD + k8)) = o;
    }
}

// CSR range allocation (wave-aggregated atomic) + dinv + packed ends + padded curs.
__global__ __launch_bounds__(256) void k_alloc(const int* __restrict__ degi,  // padded
                                               int* __restrict__ cnt,        // stride 32 ints/path
                                               int* __restrict__ offs,       // packed
                                               int* __restrict__ ends,       // packed
                                               int* __restrict__ curs,       // padded
                                               float* __restrict__ dinv) {
    const int p = blockIdx.y;
    const int i = blockIdx.x * 256 + threadIdx.x;
    const int lane = threadIdx.x & 63;
    const bool active = i < NN;
    int d = active ? degi[(p * NN + i) * PSTR] : 0;
    int incl = d;
#pragma unroll
    for (int off = 1; off < 64; off <<= 1) {
        int v = __shfl_up(incl, off);
        if (lane >= off) incl += v;
    }
    int total = __shfl(incl, 63);
    int base = 0;
    if (lane == 0) base = atomicAdd(&cnt[p * 32], total);
    base = __shfl(base, 0);
    if (active) {
        int o = base + incl - d;
        offs[p * NN + i] = o;
        ends[p * NN + i] = o + d;
        curs[(p * NN + i) * PSTR] = o;
        dinv[p * NN + i] = rsqrtf((float)d + 1.0f);
    }
}

// ---------------- mid: CSR fill ∥ f16 MFMA GEMM -----------------------------
// Fill blocks FIRST (atomic long pole); GEMM backfills the CUs.
// Fill: thread i places edge i of all 4 paths (4 independent returning
// atomics in flight, padded curs). GEMM: xws = f16(dinv * (xh @ W)).
__global__ __launch_bounds__(256) void k_mid(const _Float16* __restrict__ xh,  // [MPAD][256]
                                             const _Float16* __restrict__ Wt,  // [NP][256 n][256 k]
                                             const float* __restrict__ dinv,   // [NP][NN]
                                             _Float16* __restrict__ xws,       // [NP][NN][256]
                                             const int* __restrict__ edges,
                                             int* __restrict__ curs,           // padded
                                             int* __restrict__ srcs) {
    const int bx = blockIdx.x;
    if (bx < EDGE_BLOCKS) {
        // ---- fill part ----
        int i = bx * 256 + threadIdx.x;   // edge id within path
#pragma unroll
        for (int p = 0; p < NP; p++) {
            int src = edges[(size_t)p * 2 * NE + i];
            int dst = edges[(size_t)p * 2 * NE + NE + i];
            int pos = atomicAdd(&curs[(p * NN + dst) * PSTR], 1);
            srcs[(size_t)p * NE + pos] = src;
        }
        return;
    }
    // ---- GEMM part ----
    const int gb   = bx - EDGE_BLOCKS;
    const int p    = gb / (MPAD / 64);
    const int bm   = gb - p * (MPAD / 64);
    const int wv   = threadIdx.x >> 6;
    const int lane = threadIdx.x & 63;
    const int m_base = bm * 64;
    const int n0   = wv * 64;
    const int mr   = lane & 15;
    const int quad = lane >> 4;

    const _Float16* ap = xh + (size_t)(m_base + mr) * DD + quad * 8;
    const _Float16* bp = Wt + (size_t)p * DD * DD + (size_t)(n0 + mr) * DD + quad * 8;
    const float* dv = dinv + (size_t)p * NN;
    _Float16* cp = xws + (size_t)p * NN * DD;

    f32x4 acc[4][4] = {};   // [m-tile][n-tile]
    for (int k0 = 0; k0 < DD; k0 += 32) {
        f16x8 a[4], b[4];
#pragma unroll
        for (int i = 0; i < 4; i++) a[i] = *(const f16x8*)(ap + (size_t)i * 16 * DD + k0);
#pragma unroll
        for (int j = 0; j < 4; j++) b[j] = *(const f16x8*)(bp + (size_t)j * 16 * DD + k0);
#pragma unroll
        for (int i = 0; i < 4; i++)
#pragma unroll
            for (int j = 0; j < 4; j++)
                acc[i][j] = __builtin_amdgcn_mfma_f32_16x16x32_f16(a[i], b[j], acc[i][j], 0, 0, 0);
    }
#pragma unroll
    for (int i = 0; i < 4; i++) {
#pragma unroll
        for (int r = 0; r < 4; r++) {
            int row = m_base + i * 16 + quad * 4 + r;
            if (row < NN) {
                float d = dv[row];
#pragma unroll
                for (int j = 0; j < 4; j++)
                    cp[(size_t)row * DD + n0 + j * 16 + mr] = (_Float16)(d * acc[i][j][r]);
            }
        }
    }
}

// ---------------- fused gather + bias + MFMA semantic attention -------------
// 512 threads = 8 waves; block handles 16 nodes (64 z-rows in LDS, 33.8 KB).
__global__ __launch_bounds__(512) void k_fused(const _Float16* __restrict__ xws, // [NP][NN][256] dinv-scaled f16
                                               const float* __restrict__ dinv,   // [NP][NN]
                                               const int* __restrict__ offs,     // [NP][NN] packed
                                               const int* __restrict__ ends,     // [NP][NN] packed
                                               const int* __restrict__ srcs,     // [NP][NE]
                                               const float* __restrict__ bs,     // [NP][256]
                                               const _Float16* __restrict__ w1t, // [128 n][256 k] f16
                                               const float* __restrict__ b1,     // [128]
                                               const float* __restrict__ w2,     // [128]
                                               float* __restrict__ out) {        // [NN][256]
    const int w    = threadIdx.x >> 6;   // 0..7
    const int lane = threadIdx.x & 63;
    const int quad = lane >> 4, mr = lane & 15;
    const int half = lane >> 5, hl = lane & 31;

    // row stride 264 halves = 528 B keeps f16x8 accesses 16B-aligned.
    __shared__ __align__(16) _Float16 zs[64][264];

    union U { f16x8 v; int i4[4]; };

    // ---- gather: z[row] = dinv*(self + sum_src xws[src]) + bias, row=(node,path)
#pragma unroll 1
    for (int q = 0; q < 2; q++) {
        const int n = blockIdx.x * 16 + w * 2 + q;
#pragma unroll 1
        for (int p = 0; p < NP; p++) {
            const _Float16* xp = xws + (size_t)p * NN * DD;
            const int* sp = srcs + (size_t)p * NE;
            U acc;
#pragma unroll
            for (int t = 0; t < 4; t++) acc.i4[t] = 0;
            if (half == 0)
                acc.v = *(const f16x8*)(xp + (size_t)n * DD + hl * 8);  // self loop
            int k  = offs[p * NN + n];
            int ke = ends[p * NN + n];
            for (; k + 8 <= ke; k += 8) {
                int s0 = sp[k + half];
                int s1 = sp[k + 2 + half];
                int s2 = sp[k + 4 + half];
                int s3 = sp[k + 6 + half];
                f16x8 v0 = *(const f16x8*)(xp + (size_t)s0 * DD + hl * 8);
                f16x8 v1 = *(const f16x8*)(xp + (size_t)s1 * DD + hl * 8);
                f16x8 v2 = *(const f16x8*)(xp + (size_t)s2 * DD + hl * 8);
                f16x8 v3 = *(const f16x8*)(xp + (size_t)s3 * DD + hl * 8);
                acc.v += (v0 + v1) + (v2 + v3);
            }
            for (; k + 2 <= ke; k += 2) {
                int s0 = sp[k + half];
                acc.v += *(const f16x8*)(xp + (size_t)s0 * DD + hl * 8);
            }
            if (k < ke && half == 0)
                acc.v += *(const f16x8*)(xp + (size_t)sp[k] * DD + hl * 8);
            // combine even/odd halves
            U other;
#pragma unroll
            for (int t = 0; t < 4; t++) other.i4[t] = __shfl_xor(acc.i4[t], 32);
            acc.v += other.v;
            if (half == 0) {
                float dvv = dinv[p * NN + n];
                int row = (w * 2 + q) * 4 + p;
                f16x8 zo;
#pragma unroll
                for (int t = 0; t < 8; t++)
                    zo[t] = (_Float16)(dvv * (float)acc.v[t] + bs[p * DD + hl * 8 + t]);
                *(f16x8*)&zs[row][hl * 8] = zo;
            }
        }
    }

    __syncthreads();
    if (w >= 4) return;   // attention/combine handled by waves 0-3 (16 rows each)

    // ---- attention MFMA: H(16x128) = Z_rows(16x256) @ w1t(128x256)^T per wave
    f32x4 acch[8] = {};
    for (int k0 = 0; k0 < DD; k0 += 32) {
        f16x8 a = *(const f16x8*)&zs[w * 16 + mr][k0 + quad * 8];
#pragma unroll
        for (int j = 0; j < 8; j++) {
            f16x8 b = *(const f16x8*)(w1t + (size_t)(j * 16 + mr) * DD + k0 + quad * 8);
            acch[j] = __builtin_amdgcn_mfma_f32_16x16x32_f16(a, b, acch[j], 0, 0, 0);
        }
    }

    // ---- scores: s[path] = sum_col tanh(h + b1[col]) * w2[col]
    float part[4] = {};
#pragma unroll
    for (int j = 0; j < 8; j++) {
        int col = j * 16 + mr;
        float bb = b1[col], ww = w2[col];
#pragma unroll
        for (int r = 0; r < 4; r++)
            part[r] += tanhf(acch[j][r] + bb) * ww;
    }
#pragma unroll
    for (int off = 1; off < 16; off <<= 1) {
#pragma unroll
        for (int r = 0; r < 4; r++) part[r] += __shfl_xor(part[r], off);
    }
    float m = fmaxf(fmaxf(part[0], part[1]), fmaxf(part[2], part[3]));
    float e0 = __expf(part[0] - m), e1 = __expf(part[1] - m),
          e2 = __expf(part[2] - m), e3 = __expf(part[3] - m);
    float rr = 1.0f / (e0 + e1 + e2 + e3);
    float be[4] = {e0 * rr, e1 * rr, e2 * rr, e3 * rr};

    // ---- combine: lane handles node (w*4+quad), cols [mr*16, mr*16+16)
    const int n  = blockIdx.x * 16 + w * 4 + quad;
    const int rb = w * 16 + quad * 4;
    float o[16] = {};
#pragma unroll
    for (int p = 0; p < 4; p++) {
        f16x8 z0 = *(const f16x8*)&zs[rb + p][mr * 16];
        f16x8 z1 = *(const f16x8*)&zs[rb + p][mr * 16 + 8];
#pragma unroll
        for (int t = 0; t < 8; t++) {
            o[t]     += be[p] * (float)z0[t];
            o[t + 8] += be[p] * (float)z1[t];
        }
    }
#pragma unroll
    for (int t = 0; t < 16; t += 4)
        *(float4*)(out + (size_t)n * DD + mr * 16 + t) =
            make_float4(o[t], o[t + 1], o[t + 2], o[t + 3]);
}

extern "C" void kernel_launch(void* const* d_in, const int* in_sizes, int n_in,
                              void* d_out, int out_size, void* d_ws, size_t ws_size,
                              hipStream_t stream) {
    const float* x     = (const float*)d_in[0];
    const int*   edges = (const int*)d_in[1];   // [4][2][800000]
    const float* Ws    = (const float*)d_in[2]; // [4][256][256]
    const float* bs    = (const float*)d_in[3]; // [4][256]
    const float* w1    = (const float*)d_in[4]; // [256][128]
    const float* b1    = (const float*)d_in[5]; // [128]
    const float* w2    = (const float*)d_in[6]; // [128]
    float* out = (float*)d_out;

    char* ws = (char*)d_ws;
    int*      degi = (int*)(ws);                     // 12.8 MB (padded, 64 B/counter)
    int*      cnt  = (int*)(ws + 12800000);          // 4 paths x 128 B stride
    int*      curs = (int*)(ws + (13 << 20));        // 12.8 MB (padded)
    float*    dinv = (float*)(ws + (26 << 20));      // 800 KB
    int*      offs = (int*)(ws + (27 << 20));        // 800 KB (packed)
    int*      ends = (int*)(ws + (28 << 20));        // 800 KB (packed)
    int*      srcs = (int*)(ws + (29 << 20));        // 12.8 MB
    _Float16* Wt   = (_Float16*)(ws + (42 << 20));   // 512 KB
    _Float16* w1t  = (_Float16*)(ws + (42 << 20) + (1 << 19)); // 64 KB
    _Float16* xh   = (_Float16*)(ws + (43 << 20));   // 25.6 MB (MPAD rows)
    _Float16* xws  = (_Float16*)(ws + (69 << 20));   // 102.4 MB  -> total ~172 MB

    hipMemsetAsync(degi, 0, 12800000 + 512, stream);

    k_prep<<<EDGE_BLOCKS + CVT_BLOCKS, 256, 0, stream>>>(
        edges, degi, x, Ws, w1, xh, Wt, w1t);

    dim3 agrid((NN + 255) / 256, NP);
    k_alloc<<<agrid, 256, 0, stream>>>(degi, cnt, offs, ends, curs, dinv);

    k_mid<<<EDGE_BLOCKS + GEMM_BLOCKS, 256, 0, stream>>>(
        xh, Wt, dinv, xws, edges, curs, srcs);

    k_fused<<<NN / 16, 512, 0, stream>>>(xws, dinv, offs, ends, srcs,
                                         bs, w1t, b1, w2, out);
}